// Round 5
// baseline (524.018 us; speedup 1.0000x reference)
//
#include <hip/hip_runtime.h>
#include <math.h>

// Problem constants (X: [64, 512, 32, 32] fp32)
#define Nn   64
#define Cc   512
#define HWs  1024
#define CHW  (Cc * HWs)      // 524288
#define Mm   (Nn * HWs)      // 65536
#define EPSC 1e-5f
#define NBC  128             // ns_chain block count (grid barrier)

typedef unsigned int   u32;
typedef unsigned short u16;
typedef __attribute__((ext_vector_type(8))) short  short8;   // 8 x bf16 = 4 VGPR
typedef __attribute__((ext_vector_type(4))) float  floatx4;

__device__ __forceinline__ u16 f2bf(float f) {
    u32 u = __float_as_uint(f);
    u += 0x7fff + ((u >> 16) & 1);   // RNE
    return (u16)(u >> 16);
}
__device__ __forceinline__ float bf2f(u16 h) {
    return __uint_as_float(((u32)h) << 16);
}

__device__ __forceinline__ void gld_lds16(const u16* g, u16* l) {
    // async global->LDS, 16B per lane; LDS dest = wave-uniform base + lane*16
    __builtin_amdgcn_global_load_lds(
        (const __attribute__((address_space(1))) u32*)g,
        (__attribute__((address_space(3))) u32*)l, 16, 0, 0);
}

// ---------------------------------------------------------------------------
// K0: fp32 -> bf16 convert (natural layout) + transposed copy Xt[n][hw][c]
//     + fused per-channel partial sums into meanP[16][512] (atomics).
// Grid (16 hw-tiles, 8 c-tiles, 64 n), 256 threads.   [round-0 verified]
// ---------------------------------------------------------------------------
__global__ __launch_bounds__(256) void convert_transpose(const float* __restrict__ X,
                                                         u16* __restrict__ Xbf,
                                                         u16* __restrict__ Xt,
                                                         float* __restrict__ meanP) {
    const int hT = blockIdx.x;
    const int h0 = hT << 6;
    const int c0 = blockIdx.y << 6;
    const int n  = blockIdx.z;
    const int t  = threadIdx.x;
    __shared__ u16   T[64][65];
    __shared__ float red[64][17];

    const float* Xn  = X   + (size_t)n * CHW;
    u16*         Xbn = Xbf + (size_t)n * CHW;
    u16*         Xtn = Xt  + (size_t)n * CHW;

    const int cl = t >> 4;          // 0..15
    const int h4 = (t & 15) << 2;   // 0,4,..,60
#pragma unroll
    for (int i = 0; i < 4; ++i) {
        const int c = cl + (i << 4);
        float4 v = *(const float4*)&Xn[(size_t)(c0 + c) * HWs + h0 + h4];
        red[c][t & 15] = v.x + v.y + v.z + v.w;
        u16 b0 = f2bf(v.x), b1 = f2bf(v.y), b2 = f2bf(v.z), b3 = f2bf(v.w);
        *(ushort4*)&Xbn[(size_t)(c0 + c) * HWs + h0 + h4] = make_ushort4(b0, b1, b2, b3);
        T[c][h4]     = b0;
        T[c][h4 + 1] = b1;
        T[c][h4 + 2] = b2;
        T[c][h4 + 3] = b3;
    }
    __syncthreads();
    const int hl = t >> 4;
    const int c4 = (t & 15) << 2;
#pragma unroll
    for (int i = 0; i < 4; ++i) {
        const int h = hl + (i << 4);
        ushort4 pk = make_ushort4(T[c4][h], T[c4 + 1][h], T[c4 + 2][h], T[c4 + 3][h]);
        *(ushort4*)&Xtn[(size_t)(h0 + h) * Cc + c0 + c4] = pk;
    }
    if (t < 64) {
        float s = 0.f;
#pragma unroll
        for (int j = 0; j < 16; ++j) s += red[t][j];
        atomicAdd(&meanP[hT * 512 + c0 + t], s);
    }
}

// ---------------------------------------------------------------------------
// K2: Gram via bf16 MFMA, upper-triangle 128x128 tiles, split-K over n.
// ROUND-5: n-split 32 -> 64 (640 blocks, 2.5/CU) and double-buffered
// single-sync-per-K-step pipeline (issue k+1 overlaps compute k).  Fragment
// math identical to the round-0-verified pattern.
// ---------------------------------------------------------------------------
__global__ __launch_bounds__(256) void gram_mfma(const u16* __restrict__ Xbf,
                                                 float* __restrict__ G) {
    static const int TI[10] = {0,0,0,0,1,1,1,2,2,3};
    static const int TJ[10] = {0,1,2,3,1,2,3,2,3,3};
    const int id = blockIdx.x;
    const int q  = id >> 3;
    const int x  = q % 10;                        // tile index
    const int y  = (id & 7) + ((q / 10) << 3);    // n-split 0..63
    const int i0 = TI[x] << 7;
    const int j0 = TJ[x] << 7;
    const int n  = y;
    const int t  = threadIdx.x;
    const int w  = t >> 6, l = t & 63;

    __shared__ u16 As[2][4096];
    __shared__ u16 Bs[2][4096];

    floatx4 acc[4][4];
#pragma unroll
    for (int mi = 0; mi < 4; ++mi)
#pragma unroll
        for (int ni = 0; ni < 4; ++ni) acc[mi][ni] = (floatx4){0.f, 0.f, 0.f, 0.f};

    const int lr = l >> 2;
    const int lc = (l & 3) << 3;
    const int wm = w >> 1, wn = w & 1;
    const int fm = l & 15, fq = l >> 4;

    const u16* Xn = Xbf + (size_t)n * CHW;

    auto issue = [&](int k, int bb) {
#pragma unroll
        for (int p = 0; p < 2; ++p) {
            const int g   = w * 2 + p;
            const int row = g * 16 + lr;
            gld_lds16(Xn + (size_t)(i0 + row) * HWs + (k << 5) + lc, &As[bb][g * 512]);
            gld_lds16(Xn + (size_t)(j0 + row) * HWs + (k << 5) + lc, &Bs[bb][g * 512]);
        }
    };

    issue(0, 0);
    __syncthreads();
    for (int k = 0; k < 32; ++k) {
        if (k < 31) issue(k + 1, (k + 1) & 1);
        const int bb = k & 1;
        short8 a[4], b[4];
#pragma unroll
        for (int mi = 0; mi < 4; ++mi)
            a[mi] = *(const short8*)&As[bb][(wm * 64 + mi * 16 + fm) * 32 + fq * 8];
#pragma unroll
        for (int ni = 0; ni < 4; ++ni)
            b[ni] = *(const short8*)&Bs[bb][(wn * 64 + ni * 16 + fm) * 32 + fq * 8];
#pragma unroll
        for (int mi = 0; mi < 4; ++mi)
#pragma unroll
            for (int ni = 0; ni < 4; ++ni)
                acc[mi][ni] = __builtin_amdgcn_mfma_f32_16x16x32_bf16(
                    a[mi], b[ni], acc[mi][ni], 0, 0, 0);
        __syncthreads();   // drains vmcnt: k+1 staged; all readers done with bb
    }
#pragma unroll
    for (int mi = 0; mi < 4; ++mi)
#pragma unroll
        for (int ni = 0; ni < 4; ++ni)
#pragma unroll
            for (int r = 0; r < 4; ++r) {
                const int gi = i0 + wm * 64 + mi * 16 + fq * 4 + r;
                const int gj = j0 + wn * 64 + ni * 16 + fm;
                atomicAdd(&G[(size_t)gi * Cc + gj], acc[mi][ni][r]);
            }
}

// ---------------------------------------------------------------------------
// Grid barrier for ns_chain (NBC co-resident blocks, monotone counter).
// [round-4 verified: RELAXED atomics — acquire-per-probe caused an L2
// invalidation storm; the explicit threadfences provide the once-per-barrier
// release/acquire cache operations]
// ---------------------------------------------------------------------------
__device__ __forceinline__ void gridbar(int* bar, int gen) {
    __syncthreads();
    if (threadIdx.x == 0) {
        __threadfence();   // release: writeback dirty L2 once
        __hip_atomic_fetch_add(bar, 1, __ATOMIC_RELAXED, __HIP_MEMORY_SCOPE_AGENT);
        while (__hip_atomic_load(bar, __ATOMIC_RELAXED, __HIP_MEMORY_SCOPE_AGENT) < gen * NBC)
            __builtin_amdgcn_s_sleep(1);
        __threadfence();   // acquire: invalidate once after detection
    }
    __syncthreads();
}

// ---------------------------------------------------------------------------
// 512-K split-bf16 MFMA matmul tile, MR x 64 output per block.
// BK=64, double-buffered (2 x (2*MR+128)*64 u16 LDS), 8 pipelined chunks,
// one __syncthreads per chunk (drains vmcnt -> next chunk staged).
// Wave w stages {Ah,Al,Bh,Bl}[w]; fragment math identical to the verified
// [rows][32]-slab pattern.  C[i][j] = sum_k A[i,k]*B[j,k] (A*B^T; all
// operands symmetric).  C = alpha*(.) + beta*D; fp32 out optional.
// ---------------------------------------------------------------------------
template <int MR>
__device__ __forceinline__ void mm_bk64(const u16* Ah, const u16* Al,
                                        const u16* Bh, const u16* Bl,
                                        int i0, int j0,
                                        float alpha, const float* D, float beta,
                                        float* Cf, u16* Ch, u16* Cl, u16* S) {
    const int t = threadIdx.x, w = t >> 6, l = t & 63;
    const int wm = w >> 1, wn = w & 1, fm = l & 15, fq = l >> 4;
    const int lr = l >> 2, lc = (l & 3) << 3;
    constexpr int MI     = MR / 32;
    constexpr int OFF_AL = MR * 64;
    constexpr int OFF_BH = 2 * MR * 64;
    constexpr int OFF_BL = 2 * MR * 64 + 4096;
    constexpr int BUFSZ  = 2 * MR * 64 + 8192;

    const u16* src  = (w == 0) ? Ah : (w == 1) ? Al : (w == 2) ? Bh : Bl;
    const int rbase = (w < 2) ? i0 : j0;
    const int R     = (w < 2) ? MR : 64;
    const int OFF   = (w == 0) ? 0 : (w == 1) ? OFF_AL : (w == 2) ? OFF_BH : OFF_BL;

    floatx4 acc[MI][2];
#pragma unroll
    for (int mi = 0; mi < MI; ++mi)
#pragma unroll
        for (int ni = 0; ni < 2; ++ni) acc[mi][ni] = (floatx4){0.f, 0.f, 0.f, 0.f};

    auto issue = [&](int c, int bb) {
        u16* dst = S + bb * BUFSZ + OFF;
        const u16* sp = src + (size_t)rbase * 512 + (c << 6);
#pragma unroll
        for (int s = 0; s < 2; ++s)
#pragma unroll 4
            for (int g = 0; g < (R >> 4); ++g)
                gld_lds16(sp + (size_t)(g * 16 + lr) * 512 + s * 32 + lc,
                          dst + s * R * 32 + g * 512);
    };
    auto compute = [&](int bb) {
        const u16* base = S + bb * BUFSZ;
#pragma unroll
        for (int s = 0; s < 2; ++s) {
            short8 ah[MI], al[MI], bh[2], bl[2];
#pragma unroll
            for (int mi = 0; mi < MI; ++mi) {
                const int r = wm * (MR / 2) + mi * 16 + fm;
                const int o = s * MR * 32 + r * 32 + fq * 8;
                ah[mi] = *(const short8*)&base[o];
                al[mi] = *(const short8*)&base[OFF_AL + o];
            }
#pragma unroll
            for (int ni = 0; ni < 2; ++ni) {
                const int r = wn * 32 + ni * 16 + fm;
                const int o = s * 2048 + r * 32 + fq * 8;
                bh[ni] = *(const short8*)&base[OFF_BH + o];
                bl[ni] = *(const short8*)&base[OFF_BL + o];
            }
#pragma unroll
            for (int mi = 0; mi < MI; ++mi)
#pragma unroll
                for (int ni = 0; ni < 2; ++ni) {
                    acc[mi][ni] = __builtin_amdgcn_mfma_f32_16x16x32_bf16(ah[mi], bh[ni], acc[mi][ni], 0, 0, 0);
                    acc[mi][ni] = __builtin_amdgcn_mfma_f32_16x16x32_bf16(ah[mi], bl[ni], acc[mi][ni], 0, 0, 0);
                    acc[mi][ni] = __builtin_amdgcn_mfma_f32_16x16x32_bf16(al[mi], bh[ni], acc[mi][ni], 0, 0, 0);
                }
        }
    };

    issue(0, 0);
    __syncthreads();
    for (int c = 0; c < 8; ++c) {
        if (c < 7) issue(c + 1, (c + 1) & 1);
        compute(c & 1);
        __syncthreads();
    }

#pragma unroll
    for (int mi = 0; mi < MI; ++mi)
#pragma unroll
        for (int ni = 0; ni < 2; ++ni)
#pragma unroll
            for (int r4 = 0; r4 < 4; ++r4) {
                const int gi = i0 + wm * (MR / 2) + mi * 16 + fq * 4 + r4;
                const int gj = j0 + wn * 32 + ni * 16 + fm;
                const size_t idx = (size_t)gi * 512 + gj;
                float v = alpha * acc[mi][ni][r4];
                if (D) v += beta * D[idx];
                if (Cf) Cf[idx] = v;
                const u16 h = f2bf(v);
                Ch[idx] = h;
                Cl[idx] = f2bf(v - bf2f(h));
            }
}

// ---------------------------------------------------------------------------
// ns_chain v3: 128 blocks, 9 grid barriers.
//  setup: redundant per-block mean+trace -> LDS (no barrier)
//  sigma + P1 = 1.5I - 0.5 Sigma_N                         -> gridbar
//  4 iterations, depth-2 (P^3 S = (P*P)*(P*S)); EVERY segment uses all
//  128 blocks: stage A = 64 T2-tiles + 64 W-tiles (MR=64); stage B =
//  128 tiles of 32x64 (MR=32).
// ---------------------------------------------------------------------------
__global__ __launch_bounds__(256) void ns_chain(
    const float* G, const float* meanP, float* scal, int* bar, float* wmmv,
    u16* Sh, u16* Sl, u16* PhA, u16* PlA, u16* PhB, u16* PlB,
    u16* T2h, u16* T2l, u16* Wh, u16* Wl, float* PfA, float* PfB) {
    __shared__ u16   S[32768];    // 64 KB: 2 bufs x (2*64+128)*64
    __shared__ float meanL[512];
    __shared__ float redL[4];
    const int t = threadIdx.x, b = blockIdx.x;
    const int w = t >> 6, l = t & 63;

    // ---- setup: per-block redundant mean + trace (no grid barrier) ----
    float tp = 0.f;
#pragma unroll
    for (int cb = 0; cb < 2; ++cb) {
        const int c = t + (cb << 8);
        float s = 0.f;
#pragma unroll
        for (int q = 0; q < 16; ++q) s += meanP[(q << 9) + c];
        const float mc = s * (1.0f / Mm);
        meanL[c] = mc;
        tp += G[(size_t)c * 513] * (1.0f / Mm) - mc * mc;
    }
#pragma unroll
    for (int o = 32; o > 0; o >>= 1) tp += __shfl_xor(tp, o);
    if (l == 0) redL[w] = tp;
    __syncthreads();
    const float tr  = redL[0] + redL[1] + redL[2] + redL[3] + (float)Cc * EPSC;
    const float rtr = 1.0f / tr;
    const float sr  = sqrtf(rtr);
    if (b == 0 && t == 0) { scal[0] = rtr; scal[1] = sr; }

    // ---- sigma + P1 (rows 4b..4b+3) ----
#pragma unroll
    for (int k2 = 0; k2 < 8; ++k2) {
        const int e = (b << 11) + (k2 << 8) + t;
        const int i = e >> 9, j = e & 511;
        const float g = (i <= j) ? G[((size_t)i << 9) + j] : G[((size_t)j << 9) + i];
        float sig = g * (1.0f / Mm) - meanL[i] * meanL[j];
        if (i == j) sig += EPSC;
        const float sN = sig * rtr;
        const u16 sh = f2bf(sN);
        Sh[e] = sh;
        Sl[e] = f2bf(sN - bf2f(sh));
        const float p1 = ((i == j) ? 1.5f : 0.f) - 0.5f * sN;
        PfA[e] = p1;
        const u16 ph = f2bf(p1);
        PhA[e] = ph;
        PlA[e] = f2bf(p1 - bf2f(ph));
    }
    int gen = 0;
    gridbar(bar, ++gen);

    // ---- 4 NS iterations, depth-2, all blocks busy every segment ----
    u16 *ph = PhA, *pl = PlA, *qh = PhB, *ql = PlB;
    float *pf = PfA, *qf = PfB;
    const int i0a = ((b & 63) >> 3) << 6, j0a = (b & 7) << 6;   // 64x64, 8x8
    const int i0b = (b >> 3) << 5,        j0b = (b & 7) << 6;   // 32x64, 16x8
    for (int it = 0; it < 4; ++it) {
        if (b < 64)
            mm_bk64<64>(ph, pl, ph, pl, i0a, j0a, 1.f, nullptr, 0.f,
                        nullptr, T2h, T2l, S);                  // T2 = P*P
        else
            mm_bk64<64>(ph, pl, Sh, Sl, i0a, j0a, 1.f, nullptr, 0.f,
                        nullptr, Wh, Wl, S);                    // W = P*Sigma
        gridbar(bar, ++gen);
        mm_bk64<32>(T2h, T2l, Wh, Wl, i0b, j0b, -0.5f, pf, 1.5f,
                    qf, qh, ql, S);                             // Pn = 1.5P - .5*T2*W
        gridbar(bar, ++gen);
        { u16* x = ph; ph = qh; qh = x; }
        { u16* x = pl; pl = ql; ql = x; }
        { float* x = pf; pf = qf; qf = x; }
    }
    // 4 swaps -> final P in PfA/PhA (pf == PfA, ph == PhA here)

    // ---- wmm: wmm[c] = sqrt(rTr) * sum_j P[c][j]*mean[j] ----
    {
        const int c = (b << 2) + (t >> 6);   // 4 rows per block
        float s = 0.f;
#pragma unroll
        for (int jj = 0; jj < 8; ++jj) {
            const int j = l + (jj << 6);
            s += pf[((size_t)c << 9) + j] * meanL[j];
        }
#pragma unroll
        for (int o = 32; o > 0; o >>= 1) s += __shfl_xor(s, o);
        if (l == 0) wmmv[c] = s * sr;
    }
}

// ---------------------------------------------------------------------------
// K6: whiten via bf16 MFMA.  1D grid 2048 with XCD swizzle; LDS-staged
// epilogue with full-line stores.  ROUND-5: double-buffered single-sync
// pipeline on the 16 K-steps (fragment math unchanged).
// ---------------------------------------------------------------------------
__global__ __launch_bounds__(256) void whiten_mfma(const u16* __restrict__ Xt,
                                                   const u16* __restrict__ Pbf,
                                                   const float* __restrict__ wmm,
                                                   const float* __restrict__ scal,
                                                   float* __restrict__ out) {
    const int id  = blockIdx.x;
    const int m   = (id >> 3) & 3;                 // c'-tile (member)
    const int grp = (id & 7) + ((id >> 5) << 3);   // 0..511
    const int c0  = m << 7;
    const int h0  = (grp & 7) << 7;
    const int n   = grp >> 3;
    const int t   = threadIdx.x;
    const int w   = t >> 6, l = t & 63;

    __shared__ char smem[128 * 68 * 4];            // 34816 B
    u16* AsB = (u16*)smem;                         // [2][4096]
    u16* BsB = AsB + 8192;                         // [2][4096]
    float* Ep = (float*)smem;                      // epilogue tile [128][68]

    floatx4 acc[4][4];
#pragma unroll
    for (int mi = 0; mi < 4; ++mi)
#pragma unroll
        for (int ni = 0; ni < 4; ++ni) acc[mi][ni] = (floatx4){0.f, 0.f, 0.f, 0.f};

    const int lr = l >> 2;
    const int lc = (l & 3) << 3;
    const int wm = w >> 1, wn = w & 1;
    const int fm = l & 15, fq = l >> 4;

    const u16* Xn = Xt + (size_t)n * CHW;

    auto issue = [&](int k, int bb) {
#pragma unroll
        for (int p = 0; p < 2; ++p) {
            const int g   = w * 2 + p;
            const int row = g * 16 + lr;
            gld_lds16(Xn  + (size_t)(h0 + row) * Cc + (k << 5) + lc, &AsB[bb * 4096 + g * 512]);
            gld_lds16(Pbf + (size_t)(c0 + row) * Cc + (k << 5) + lc, &BsB[bb * 4096 + g * 512]);
        }
    };

    issue(0, 0);
    __syncthreads();
    for (int k = 0; k < 16; ++k) {
        if (k < 15) issue(k + 1, (k + 1) & 1);
        const int bb = k & 1;
        short8 a[4], b[4];
#pragma unroll
        for (int mi = 0; mi < 4; ++mi)
            a[mi] = *(const short8*)&AsB[bb * 4096 + (wm * 64 + mi * 16 + fm) * 32 + fq * 8];
#pragma unroll
        for (int ni = 0; ni < 4; ++ni)
            b[ni] = *(const short8*)&BsB[bb * 4096 + (wn * 64 + ni * 16 + fm) * 32 + fq * 8];
#pragma unroll
        for (int mi = 0; mi < 4; ++mi)
#pragma unroll
            for (int ni = 0; ni < 4; ++ni)
                acc[mi][ni] = __builtin_amdgcn_mfma_f32_16x16x32_bf16(
                    a[mi], b[ni], acc[mi][ni], 0, 0, 0);
        __syncthreads();
    }

    const float sr = scal[1];
    float wv[4];
#pragma unroll
    for (int ni = 0; ni < 4; ++ni) wv[ni] = wmm[c0 + wn * 64 + ni * 16 + fm];
    float* outn = out + (size_t)n * CHW;

#pragma unroll
    for (int mp = 0; mp < 2; ++mp) {
        __syncthreads();
#pragma unroll
        for (int p = 0; p < 2; ++p) {
            const int mi = mp * 2 + p;
#pragma unroll
            for (int ni = 0; ni < 4; ++ni) {
                const int row  = wn * 64 + ni * 16 + fm;
                const int slot = wm * 32 + p * 16 + fq * 4;
                floatx4 v = acc[mi][ni] * sr - wv[ni];
                *(floatx4*)&Ep[row * 68 + slot] = v;
            }
        }
        __syncthreads();
#pragma unroll
        for (int jj = 0; jj < 8; ++jj) {
            const int idx = jj * 256 + t;          // 2048 float4
            const int row = idx >> 4;
            const int s4  = (idx & 15) << 2;       // 0..60
            const int wmr = s4 >> 5;
            const int within = s4 & 31;
            float4 v = *(const float4*)&Ep[row * 68 + s4];
            *(float4*)&outn[(size_t)(c0 + row) * HWs + h0 + wmr * 64 + mp * 32 + within] = v;
        }
    }
}

// ---------------------------------------------------------------------------
// Fallback fp32 kernels (used only if ws too small)
// ---------------------------------------------------------------------------
__global__ __launch_bounds__(256) void mean_kernel(const float* __restrict__ X,
                                                   float* __restrict__ mean) {
    const int c = blockIdx.x;
    const int t = threadIdx.x;
    float s = 0.f;
    for (int n = 0; n < Nn; ++n) {
        const float4* p = (const float4*)(X + (size_t)n * CHW + (size_t)c * HWs);
        float4 v = p[t];
        s += v.x + v.y + v.z + v.w;
    }
    __shared__ float red[256];
    red[t] = s;
    __syncthreads();
    for (int o = 128; o > 0; o >>= 1) {
        if (t < o) red[t] += red[t + o];
        __syncthreads();
    }
    if (t == 0) mean[c] = red[0] * (1.0f / Mm);
}

__global__ __launch_bounds__(256) void trace_fb(const float* __restrict__ G,
                                                const float* __restrict__ mean,
                                                float* __restrict__ scal) {
    const int t = threadIdx.x;
    float s = 0.f;
    for (int i = t; i < Cc; i += 256)
        s += G[(size_t)i * Cc + i] * (1.0f / Mm) - mean[i] * mean[i];
    __shared__ float red[256];
    red[t] = s;
    __syncthreads();
    for (int o = 128; o > 0; o >>= 1) {
        if (t < o) red[t] += red[t + o];
        __syncthreads();
    }
    if (t == 0) {
        const float tr  = red[0] + (float)Cc * EPSC;
        const float rtr = 1.0f / tr;
        scal[0] = rtr;
        scal[1] = sqrtf(rtr);
    }
}

__global__ __launch_bounds__(256) void gram_kernel(const float* __restrict__ X,
                                                   float* __restrict__ G) {
    const int ti = blockIdx.x >> 3, tj = blockIdx.x & 7;
    const int i0 = ti << 6, j0 = tj << 6;
    const int n0 = blockIdx.y << 3;
    const int t  = threadIdx.x;
    const int tx = t & 15, ty = t >> 4;
    __shared__ float As[64][33];
    __shared__ float Bs[64][33];
    float acc[4][4] = {};
    const int lc = t & 31;
    const int lr0 = t >> 5;
    for (int n = n0; n < n0 + 8; ++n) {
        const float* Xn = X + (size_t)n * CHW;
        for (int hw0 = 0; hw0 < HWs; hw0 += 32) {
#pragma unroll
            for (int r = 0; r < 8; ++r) {
                const int row = lr0 + (r << 3);
                As[row][lc] = Xn[(size_t)(i0 + row) * HWs + hw0 + lc];
                Bs[row][lc] = Xn[(size_t)(j0 + row) * HWs + hw0 + lc];
            }
            __syncthreads();
#pragma unroll
            for (int k = 0; k < 32; ++k) {
                float a[4], b[4];
#pragma unroll
                for (int r = 0; r < 4; ++r) a[r] = As[(ty << 2) + r][k];
#pragma unroll
                for (int cn = 0; cn < 4; ++cn) b[cn] = Bs[(tx << 2) + cn][k];
#pragma unroll
                for (int r = 0; r < 4; ++r)
#pragma unroll
                    for (int cn = 0; cn < 4; ++cn) acc[r][cn] += a[r] * b[cn];
            }
            __syncthreads();
        }
    }
#pragma unroll
    for (int r = 0; r < 4; ++r)
#pragma unroll
        for (int cn = 0; cn < 4; ++cn)
            atomicAdd(&G[(size_t)(i0 + (ty << 2) + r) * Cc + j0 + (tx << 2) + cn],
                      acc[r][cn]);
}

__global__ __launch_bounds__(256) void sigman_full_kernel(const float* __restrict__ G,
                                                          const float* __restrict__ mean,
                                                          const float* __restrict__ scal,
                                                          float* __restrict__ S,
                                                          float* __restrict__ P) {
    const int e = blockIdx.x * 256 + threadIdx.x;
    const int i = e >> 9, j = e & 511;
    const float rtr = scal[0];
    float sig = G[e] * (1.0f / Mm) - mean[i] * mean[j];
    if (i == j) sig += EPSC;
    S[e] = sig * rtr;
    P[e] = (i == j) ? 1.f : 0.f;
}

__global__ __launch_bounds__(256) void mm512_kernel(const float* __restrict__ A,
                                                    const float* __restrict__ B,
                                                    float* __restrict__ C,
                                                    float alpha,
                                                    const float* __restrict__ D,
                                                    float beta) {
    const int ti = blockIdx.x >> 3, tj = blockIdx.x & 7;
    const int i0 = ti << 6, j0 = tj << 6;
    const int t  = threadIdx.x;
    const int tx = t & 15, ty = t >> 4;
    __shared__ float As[64][33];
    __shared__ float Bs[32][65];
    float acc[4][4] = {};
    const int lcA = t & 31, lrA = t >> 5;
    const int lcB = t & 63, lrB = t >> 6;
    for (int k0 = 0; k0 < 512; k0 += 32) {
#pragma unroll
        for (int r = 0; r < 8; ++r) {
            const int row = lrA + (r << 3);
            As[row][lcA] = A[(size_t)(i0 + row) * 512 + k0 + lcA];
        }
#pragma unroll
        for (int r = 0; r < 8; ++r) {
            const int row = lrB + (r << 2);
            Bs[row][lcB] = B[(size_t)(k0 + row) * 512 + j0 + lcB];
        }
        __syncthreads();
#pragma unroll
        for (int k = 0; k < 32; ++k) {
            float a[4], b[4];
#pragma unroll
            for (int r = 0; r < 4; ++r) a[r] = As[(ty << 2) + r][k];
#pragma unroll
            for (int cn = 0; cn < 4; ++cn) b[cn] = Bs[k][(tx << 2) + cn];
#pragma unroll
            for (int r = 0; r < 4; ++r)
#pragma unroll
                for (int cn = 0; cn < 4; ++cn) acc[r][cn] += a[r] * b[cn];
        }
        __syncthreads();
    }
#pragma unroll
    for (int r = 0; r < 4; ++r) {
        const size_t idx = (size_t)(i0 + (ty << 2) + r) * 512 + j0 + (tx << 2);
        float4 v;
        v.x = alpha * acc[r][0];
        v.y = alpha * acc[r][1];
        v.z = alpha * acc[r][2];
        v.w = alpha * acc[r][3];
        if (D) {
            const float4 d = *(const float4*)(D + idx);
            v.x += beta * d.x; v.y += beta * d.y; v.z += beta * d.z; v.w += beta * d.w;
        }
        *(float4*)(C + idx) = v;
    }
}

__global__ __launch_bounds__(128) void wmm_kernel(const float* __restrict__ P,
                                                  const float* __restrict__ mean,
                                                  const float* __restrict__ scal,
                                                  float* __restrict__ wmm) {
    const int c = blockIdx.x, t = threadIdx.x;
    float s = 0.f;
    for (int j = t; j < Cc; j += 128) s += P[(size_t)c * Cc + j] * mean[j];
    __shared__ float red[128];
    red[t] = s;
    __syncthreads();
    for (int o = 64; o > 0; o >>= 1) {
        if (t < o) red[t] += red[t + o];
        __syncthreads();
    }
    if (t == 0) wmm[c] = red[0] * scal[1];
}

__global__ __launch_bounds__(256) void whiten_kernel(const float* __restrict__ X,
                                                     const float* __restrict__ P,
                                                     const float* __restrict__ wmm,
                                                     const float* __restrict__ scal,
                                                     float* __restrict__ out) {
    const int c0 = blockIdx.x << 6;
    const int h0 = blockIdx.y << 6;
    const int n  = blockIdx.z;
    const int t  = threadIdx.x;
    const int tx = t & 15, ty = t >> 4;
    __shared__ float Ps[64][33];
    __shared__ float Xs[32][65];
    float acc[4][4] = {};
    const int lcA = t & 31, lrA = t >> 5;
    const int lcB = t & 63, lrB = t >> 6;
    const float* Xn = X + (size_t)n * CHW;
    for (int k0 = 0; k0 < 512; k0 += 32) {
#pragma unroll
        for (int r = 0; r < 8; ++r) {
            const int row = lrA + (r << 3);
            Ps[row][lcA] = P[(size_t)(c0 + row) * 512 + k0 + lcA];
        }
#pragma unroll
        for (int r = 0; r < 8; ++r) {
            const int row = lrB + (r << 2);
            Xs[row][lcB] = Xn[(size_t)(k0 + row) * HWs + h0 + lcB];
        }
        __syncthreads();
#pragma unroll
        for (int k = 0; k < 32; ++k) {
            float a[4], b[4];
#pragma unroll
            for (int r = 0; r < 4; ++r) a[r] = Ps[(ty << 2) + r][k];
#pragma unroll
            for (int cn = 0; cn < 4; ++cn) b[cn] = Xs[k][(tx << 2) + cn];
#pragma unroll
            for (int r = 0; r < 4; ++r)
#pragma unroll
                for (int cn = 0; cn < 4; ++cn) acc[r][cn] += a[r] * b[cn];
        }
        __syncthreads();
    }
    const float sr = scal[1];
#pragma unroll
    for (int r = 0; r < 4; ++r) {
        const int c = c0 + (ty << 2) + r;
        const float wv = wmm[c];
        float4 v;
        v.x = sr * acc[r][0] - wv;
        v.y = sr * acc[r][1] - wv;
        v.z = sr * acc[r][2] - wv;
        v.w = sr * acc[r][3] - wv;
        *(float4*)(out + (size_t)n * CHW + (size_t)c * HWs + h0 + (tx << 2)) = v;
    }
}

// ---------------------------------------------------------------------------
extern "C" void kernel_launch(void* const* d_in, const int* in_sizes, int n_in,
                              void* d_out, int out_size, void* d_ws, size_t ws_size,
                              hipStream_t stream) {
    const float* X = (const float*)d_in[0];
    float* out     = (float*)d_out;

    const size_t NU16 = 33554432;   // CHW*Nn
    const size_t NM   = 262144;     // 512*512
    const size_t NEED = NU16 * 2 * 2                              // Xbf + Xt
                      + NM * 10 * 2                               // 10 bf16 512x512 mats
                      + (NM + 8192 + 32 + 512 + 512 + 2 * NM) * 4;// G,meanP,scal+bar,mean,wmm,PfA/B

    if (ws_size >= NEED) {
        u16* Xbf = (u16*)d_ws;
        u16* Xt  = Xbf + NU16;
        u16* Sh  = Xt  + NU16;
        u16* Sl  = Sh + NM;
        u16* PhA = Sl + NM;
        u16* PlA = PhA + NM;
        u16* PhB = PlA + NM;
        u16* PlB = PhB + NM;
        u16* T2h = PlB + NM;
        u16* T2l = T2h + NM;
        u16* Wh  = T2l + NM;
        u16* Wl  = Wh + NM;
        float* G     = (float*)(Wl + NM);
        float* meanP = G + NM;               // 16*512 partials
        float* scal  = meanP + 8192;         // 16 floats
        int*   bar   = (int*)(scal + 16);    // 16 ints (grid barrier)
        float* mean  = (float*)(bar + 16);   // 512 (unused in fast path)
        float* wmm   = mean + 512;           // 512
        float* PfA   = wmm + 512;            // 262144
        float* PfB   = PfA + NM;             // 262144

        // zero G + meanP + scal + bar in one memset (contiguous)
        hipMemsetAsync(G, 0, (NM + 8192 + 32) * sizeof(float), stream);
        convert_transpose<<<dim3(16, 8, 64), 256, 0, stream>>>(X, Xbf, Xt, meanP);
        gram_mfma<<<640, 256, 0, stream>>>(Xbf, G);
        ns_chain<<<NBC, 256, 0, stream>>>(G, meanP, scal, bar, wmm,
                                          Sh, Sl, PhA, PlA, PhB, PlB,
                                          T2h, T2l, Wh, Wl, PfA, PfB);
        whiten_mfma<<<2048, 256, 0, stream>>>(Xt, PhA, wmm, scal, out);
    } else {
        // fallback: fp32 path (~6.3 MB ws)
        float* ws   = (float*)d_ws;
        float* mean = ws;
        float* wmm  = ws + 512;
        float* scal = ws + 1024;
        float* G    = ws + 2048;
        float* S    = G + 262144;
        float* Pa   = S + 262144;
        float* Pb   = Pa + 262144;
        float* P2   = Pb + 262144;
        float* P3   = P2 + 262144;

        mean_kernel<<<512, 256, 0, stream>>>(X, mean);
        hipMemsetAsync(G, 0, sizeof(float) * 262144, stream);
        gram_kernel<<<dim3(64, 8), 256, 0, stream>>>(X, G);
        trace_fb<<<1, 256, 0, stream>>>(G, mean, scal);
        sigman_full_kernel<<<1024, 256, 0, stream>>>(G, mean, scal, S, Pa);

        float* P  = Pa;
        float* Pn = Pb;
        for (int it = 0; it < 5; ++it) {
            mm512_kernel<<<64, 256, 0, stream>>>(P, P, P2, 1.f, nullptr, 0.f);
            mm512_kernel<<<64, 256, 0, stream>>>(P2, P, P3, 1.f, nullptr, 0.f);
            mm512_kernel<<<64, 256, 0, stream>>>(P3, S, Pn, -0.5f, P, 1.5f);
            float* tmp = P; P = Pn; Pn = tmp;
        }

        wmm_kernel<<<512, 128, 0, stream>>>(P, mean, scal, wmm);
        whiten_kernel<<<dim3(8, 16, 64), 256, 0, stream>>>(X, P, wmm, scal, out);
    }
}

// Round 6
// 467.742 us; speedup vs baseline: 1.1203x; 1.1203x over previous
//
#include <hip/hip_runtime.h>
#include <math.h>

// Problem constants (X: [64, 512, 32, 32] fp32)
#define Nn   64
#define Cc   512
#define HWs  1024
#define CHW  (Cc * HWs)      // 524288
#define Mm   (Nn * HWs)      // 65536
#define EPSC 1e-5f
#define NBC  128             // ns_chain block count (grid barrier)

typedef unsigned int   u32;
typedef unsigned short u16;
typedef unsigned long long u64;
typedef __attribute__((ext_vector_type(8))) short  short8;   // 8 x bf16 = 4 VGPR
typedef __attribute__((ext_vector_type(4))) float  floatx4;

__device__ __forceinline__ u16 f2bf(float f) {
    u32 u = __float_as_uint(f);
    u += 0x7fff + ((u >> 16) & 1);   // RNE
    return (u16)(u >> 16);
}
__device__ __forceinline__ float bf2f(u16 h) {
    return __uint_as_float(((u32)h) << 16);
}

__device__ __forceinline__ void gld_lds16(const u16* g, u16* l) {
    // async global->LDS, 16B per lane; LDS dest = wave-uniform base + lane*16
    __builtin_amdgcn_global_load_lds(
        (const __attribute__((address_space(1))) u32*)g,
        (__attribute__((address_space(3))) u32*)l, 16, 0, 0);
}

// sc0|sc1 cache policy (gfx940+ CPol: SC0=1, NT=2, SC1=16): read/write the
// device coherence point, bypassing (and not polluting/invalidating) L1/L2.
#define AUX_SC 0x11

__device__ __forceinline__ void gld_lds16_sc(const u16* g, u16* l) {
    __builtin_amdgcn_global_load_lds(
        (const __attribute__((address_space(1))) u32*)g,
        (__attribute__((address_space(3))) u32*)l, 16, 0, AUX_SC);
}
// 8-byte coherent store (4 packed bf16)
__device__ __forceinline__ void st8_sc(u16* p, u64 pk) {
    asm volatile("global_store_dwordx2 %0, %1, off sc0 sc1"
                 :: "v"(p), "v"(pk) : "memory");
}
__device__ __forceinline__ u64 pk4(const u16* h) {
    return (u64)h[0] | ((u64)h[1] << 16) | ((u64)h[2] << 32) | ((u64)h[3] << 48);
}

// ---------------------------------------------------------------------------
// K0: fp32 -> bf16 convert (natural layout) + transposed copy Xt[n][hw][c]
//     + fused per-channel partial sums into meanP[16][512] (atomics).
// Grid (16 hw-tiles, 8 c-tiles, 64 n), 256 threads.   [round-0 verified]
// ---------------------------------------------------------------------------
__global__ __launch_bounds__(256) void convert_transpose(const float* __restrict__ X,
                                                         u16* __restrict__ Xbf,
                                                         u16* __restrict__ Xt,
                                                         float* __restrict__ meanP) {
    const int hT = blockIdx.x;
    const int h0 = hT << 6;
    const int c0 = blockIdx.y << 6;
    const int n  = blockIdx.z;
    const int t  = threadIdx.x;
    __shared__ u16   T[64][65];
    __shared__ float red[64][17];

    const float* Xn  = X   + (size_t)n * CHW;
    u16*         Xbn = Xbf + (size_t)n * CHW;
    u16*         Xtn = Xt  + (size_t)n * CHW;

    const int cl = t >> 4;          // 0..15
    const int h4 = (t & 15) << 2;   // 0,4,..,60
#pragma unroll
    for (int i = 0; i < 4; ++i) {
        const int c = cl + (i << 4);
        float4 v = *(const float4*)&Xn[(size_t)(c0 + c) * HWs + h0 + h4];
        red[c][t & 15] = v.x + v.y + v.z + v.w;
        u16 b0 = f2bf(v.x), b1 = f2bf(v.y), b2 = f2bf(v.z), b3 = f2bf(v.w);
        *(ushort4*)&Xbn[(size_t)(c0 + c) * HWs + h0 + h4] = make_ushort4(b0, b1, b2, b3);
        T[c][h4]     = b0;
        T[c][h4 + 1] = b1;
        T[c][h4 + 2] = b2;
        T[c][h4 + 3] = b3;
    }
    __syncthreads();
    const int hl = t >> 4;
    const int c4 = (t & 15) << 2;
#pragma unroll
    for (int i = 0; i < 4; ++i) {
        const int h = hl + (i << 4);
        ushort4 pk = make_ushort4(T[c4][h], T[c4 + 1][h], T[c4 + 2][h], T[c4 + 3][h]);
        *(ushort4*)&Xtn[(size_t)(h0 + h) * Cc + c0 + c4] = pk;
    }
    if (t < 64) {
        float s = 0.f;
#pragma unroll
        for (int j = 0; j < 16; ++j) s += red[t][j];
        atomicAdd(&meanP[hT * 512 + c0 + t], s);
    }
}

// ---------------------------------------------------------------------------
// K2: Gram via bf16 MFMA, upper-triangle 128x128 tiles, split-K over n.
// [round-5 verified]
// ---------------------------------------------------------------------------
__global__ __launch_bounds__(256) void gram_mfma(const u16* __restrict__ Xbf,
                                                 float* __restrict__ G) {
    static const int TI[10] = {0,0,0,0,1,1,1,2,2,3};
    static const int TJ[10] = {0,1,2,3,1,2,3,2,3,3};
    const int id = blockIdx.x;
    const int q  = id >> 3;
    const int x  = q % 10;                        // tile index
    const int y  = (id & 7) + ((q / 10) << 3);    // n-split 0..63
    const int i0 = TI[x] << 7;
    const int j0 = TJ[x] << 7;
    const int n  = y;
    const int t  = threadIdx.x;
    const int w  = t >> 6, l = t & 63;

    __shared__ u16 As[2][4096];
    __shared__ u16 Bs[2][4096];

    floatx4 acc[4][4];
#pragma unroll
    for (int mi = 0; mi < 4; ++mi)
#pragma unroll
        for (int ni = 0; ni < 4; ++ni) acc[mi][ni] = (floatx4){0.f, 0.f, 0.f, 0.f};

    const int lr = l >> 2;
    const int lc = (l & 3) << 3;
    const int wm = w >> 1, wn = w & 1;
    const int fm = l & 15, fq = l >> 4;

    const u16* Xn = Xbf + (size_t)n * CHW;

    auto issue = [&](int k, int bb) {
#pragma unroll
        for (int p = 0; p < 2; ++p) {
            const int g   = w * 2 + p;
            const int row = g * 16 + lr;
            gld_lds16(Xn + (size_t)(i0 + row) * HWs + (k << 5) + lc, &As[bb][g * 512]);
            gld_lds16(Xn + (size_t)(j0 + row) * HWs + (k << 5) + lc, &Bs[bb][g * 512]);
        }
    };

    issue(0, 0);
    __syncthreads();
    for (int k = 0; k < 32; ++k) {
        if (k < 31) issue(k + 1, (k + 1) & 1);
        const int bb = k & 1;
        short8 a[4], b[4];
#pragma unroll
        for (int mi = 0; mi < 4; ++mi)
            a[mi] = *(const short8*)&As[bb][(wm * 64 + mi * 16 + fm) * 32 + fq * 8];
#pragma unroll
        for (int ni = 0; ni < 4; ++ni)
            b[ni] = *(const short8*)&Bs[bb][(wn * 64 + ni * 16 + fm) * 32 + fq * 8];
#pragma unroll
        for (int mi = 0; mi < 4; ++mi)
#pragma unroll
            for (int ni = 0; ni < 4; ++ni)
                acc[mi][ni] = __builtin_amdgcn_mfma_f32_16x16x32_bf16(
                    a[mi], b[ni], acc[mi][ni], 0, 0, 0);
        __syncthreads();   // drains vmcnt: k+1 staged; all readers done with bb
    }
#pragma unroll
    for (int mi = 0; mi < 4; ++mi)
#pragma unroll
        for (int ni = 0; ni < 4; ++ni)
#pragma unroll
            for (int r = 0; r < 4; ++r) {
                const int gi = i0 + wm * 64 + mi * 16 + fq * 4 + r;
                const int gj = j0 + wn * 64 + ni * 16 + fm;
                atomicAdd(&G[(size_t)gi * Cc + gj], acc[mi][ni][r]);
            }
}

// ---------------------------------------------------------------------------
// Grid barrier, ROUND-6: NO threadfences.  All cross-block chain data moves
// via sc0|sc1 accesses (coherence point), so the per-barrier buffer_wbl2 +
// buffer_inv pair (whole-XCD L2 destruction, 2 per block per barrier) is not
// needed.  Explicit vmcnt(0) drains the inline-asm sc stores (the compiler
// does not track them); __syncthreads then orders all waves' stores before
// thread 0's counter atomic (relaxed agent = coherent point, R4-verified).
// ---------------------------------------------------------------------------
__device__ __forceinline__ void gridbar(int* bar, int gen) {
    asm volatile("s_waitcnt vmcnt(0)" ::: "memory");
    __syncthreads();
    if (threadIdx.x == 0) {
        __hip_atomic_fetch_add(bar, 1, __ATOMIC_RELAXED, __HIP_MEMORY_SCOPE_AGENT);
        while (__hip_atomic_load(bar, __ATOMIC_RELAXED, __HIP_MEMORY_SCOPE_AGENT) < gen * NBC)
            __builtin_amdgcn_s_sleep(1);
    }
    __syncthreads();
}

// ---------------------------------------------------------------------------
// 512-K split-bf16 MFMA matmul tile, MR x 64 output per block.
// BK=64, double-buffered, 8 pipelined chunks.  [round-5 verified structure]
// ROUND-6: operand staging via sc loads (coherence point); bf16 hi/lo C
// written TRANSPOSED (all chain matrices are symmetric) as packed 8B sc
// stores -> coherent without fences AND 4x better store coalescing.
// fp32 D/Cf (the P ping-pong) stay plain cached: with the tile-matched
// distribution every block reads/writes only its OWN D/Cf tile.
// ---------------------------------------------------------------------------
template <int MR>
__device__ __forceinline__ void mm_bk64(const u16* Ah, const u16* Al,
                                        const u16* Bh, const u16* Bl,
                                        int i0, int j0,
                                        float alpha, const float* D, float beta,
                                        float* Cf, u16* Ch, u16* Cl, u16* S) {
    const int t = threadIdx.x, w = t >> 6, l = t & 63;
    const int wm = w >> 1, wn = w & 1, fm = l & 15, fq = l >> 4;
    const int lr = l >> 2, lc = (l & 3) << 3;
    constexpr int MI     = MR / 32;
    constexpr int OFF_AL = MR * 64;
    constexpr int OFF_BH = 2 * MR * 64;
    constexpr int OFF_BL = 2 * MR * 64 + 4096;
    constexpr int BUFSZ  = 2 * MR * 64 + 8192;

    const u16* src  = (w == 0) ? Ah : (w == 1) ? Al : (w == 2) ? Bh : Bl;
    const int rbase = (w < 2) ? i0 : j0;
    const int R     = (w < 2) ? MR : 64;
    const int OFF   = (w == 0) ? 0 : (w == 1) ? OFF_AL : (w == 2) ? OFF_BH : OFF_BL;

    floatx4 acc[MI][2];
#pragma unroll
    for (int mi = 0; mi < MI; ++mi)
#pragma unroll
        for (int ni = 0; ni < 2; ++ni) acc[mi][ni] = (floatx4){0.f, 0.f, 0.f, 0.f};

    auto issue = [&](int c, int bb) {
        u16* dst = S + bb * BUFSZ + OFF;
        const u16* sp = src + (size_t)rbase * 512 + (c << 6);
#pragma unroll
        for (int s = 0; s < 2; ++s)
#pragma unroll 4
            for (int g = 0; g < (R >> 4); ++g)
                gld_lds16_sc(sp + (size_t)(g * 16 + lr) * 512 + s * 32 + lc,
                             dst + s * R * 32 + g * 512);
    };
    auto compute = [&](int bb) {
        const u16* base = S + bb * BUFSZ;
#pragma unroll
        for (int s = 0; s < 2; ++s) {
            short8 ah[MI], al[MI], bh[2], bl[2];
#pragma unroll
            for (int mi = 0; mi < MI; ++mi) {
                const int r = wm * (MR / 2) + mi * 16 + fm;
                const int o = s * MR * 32 + r * 32 + fq * 8;
                ah[mi] = *(const short8*)&base[o];
                al[mi] = *(const short8*)&base[OFF_AL + o];
            }
#pragma unroll
            for (int ni = 0; ni < 2; ++ni) {
                const int r = wn * 32 + ni * 16 + fm;
                const int o = s * 2048 + r * 32 + fq * 8;
                bh[ni] = *(const short8*)&base[OFF_BH + o];
                bl[ni] = *(const short8*)&base[OFF_BL + o];
            }
#pragma unroll
            for (int mi = 0; mi < MI; ++mi)
#pragma unroll
                for (int ni = 0; ni < 2; ++ni) {
                    acc[mi][ni] = __builtin_amdgcn_mfma_f32_16x16x32_bf16(ah[mi], bh[ni], acc[mi][ni], 0, 0, 0);
                    acc[mi][ni] = __builtin_amdgcn_mfma_f32_16x16x32_bf16(ah[mi], bl[ni], acc[mi][ni], 0, 0, 0);
                    acc[mi][ni] = __builtin_amdgcn_mfma_f32_16x16x32_bf16(al[mi], bh[ni], acc[mi][ni], 0, 0, 0);
                }
        }
    };

    issue(0, 0);
    __syncthreads();
    for (int c = 0; c < 8; ++c) {
        if (c < 7) issue(c + 1, (c + 1) & 1);
        compute(c & 1);
        __syncthreads();
    }

#pragma unroll
    for (int mi = 0; mi < MI; ++mi)
#pragma unroll
        for (int ni = 0; ni < 2; ++ni) {
            const int gib = i0 + wm * (MR / 2) + mi * 16 + fq * 4;   // row base
            const int gj  = j0 + wn * 32 + ni * 16 + fm;
            u16 h[4], lo[4];
#pragma unroll
            for (int r4 = 0; r4 < 4; ++r4) {
                float v = alpha * acc[mi][ni][r4];
                if (D) v += beta * D[(size_t)(gib + r4) * 512 + gj];
                if (Cf) Cf[(size_t)(gib + r4) * 512 + gj] = v;
                h[r4]  = f2bf(v);
                lo[r4] = f2bf(v - bf2f(h[r4]));
            }
            // symmetric matrix: store transposed row (gj, gib..gib+3), 8B packed
            st8_sc(&Ch[(size_t)gj * 512 + gib], pk4(h));
            st8_sc(&Cl[(size_t)gj * 512 + gib], pk4(lo));
        }
}

// ---------------------------------------------------------------------------
// ns_chain v4: 128 blocks, 9 grid barriers, fence-free coherence.
//  setup: redundant per-block mean+trace -> LDS (no barrier)
//  sigma + P1 (tile-matched 32x64 distribution; sc stores for bf16,
//              plain block-local stores for fp32 P)        -> gridbar
//  4 iterations, depth-2 (P^3 S = (P*P)*(P*S)); stage A = 128 blocks of
//  64x64 (T2 | W); stage B = 128 blocks of 32x64 (own tile).
//  wmm: per-block own-tile partial, atomicAdd combine.
// ---------------------------------------------------------------------------
__global__ __launch_bounds__(256) void ns_chain(
    const float* G, const float* meanP, float* scal, int* bar, float* wmmv,
    u16* Sh, u16* Sl, u16* PhA, u16* PlA, u16* PhB, u16* PlB,
    u16* T2h, u16* T2l, u16* Wh, u16* Wl, float* PfA, float* PfB) {
    __shared__ u16   S[32768];    // 64 KB: 2 bufs x (2*64+128)*64
    __shared__ float meanL[512];
    __shared__ float redL[4];
    const int t = threadIdx.x, b = blockIdx.x;
    const int w = t >> 6, l = t & 63;

    // ---- setup: per-block redundant mean + trace (no grid barrier) ----
    float tp = 0.f;
#pragma unroll
    for (int cb = 0; cb < 2; ++cb) {
        const int c = t + (cb << 8);
        float s = 0.f;
#pragma unroll
        for (int q = 0; q < 16; ++q) s += meanP[(q << 9) + c];
        const float mc = s * (1.0f / Mm);
        meanL[c] = mc;
        tp += G[(size_t)c * 513] * (1.0f / Mm) - mc * mc;
    }
#pragma unroll
    for (int o = 32; o > 0; o >>= 1) tp += __shfl_xor(tp, o);
    if (l == 0) redL[w] = tp;
    __syncthreads();
    const float tr  = redL[0] + redL[1] + redL[2] + redL[3] + (float)Cc * EPSC;
    const float rtr = 1.0f / tr;
    const float sr  = sqrtf(rtr);
    if (b == 0 && t == 0) { scal[0] = rtr; scal[1] = sr; }

    // ---- sigma + P1, tile-matched distribution (rows R0..R0+31, cols C0..C0+63)
    const int R0 = (b >> 3) << 5;
    const int C0 = (b & 7) << 6;
#pragma unroll
    for (int k2 = 0; k2 < 2; ++k2) {
        const int idx4 = (k2 << 8) + t;          // 0..511
        const int i  = R0 + (idx4 >> 4);
        const int jb = C0 + ((idx4 & 15) << 2);
        float p1[4];
        u16 sh[4], sl[4], ph[4], pl[4];
#pragma unroll
        for (int u = 0; u < 4; ++u) {
            const int j = jb + u;
            const float g = (i <= j) ? G[((size_t)i << 9) + j] : G[((size_t)j << 9) + i];
            float sig = g * (1.0f / Mm) - meanL[i] * meanL[j];
            if (i == j) sig += EPSC;
            const float sN = sig * rtr;
            sh[u] = f2bf(sN);
            sl[u] = f2bf(sN - bf2f(sh[u]));
            p1[u] = ((i == j) ? 1.5f : 0.f) - 0.5f * sN;
            ph[u] = f2bf(p1[u]);
            pl[u] = f2bf(p1[u] - bf2f(ph[u]));
        }
        const size_t e = ((size_t)i << 9) + jb;
        st8_sc(&Sh[e],  pk4(sh));
        st8_sc(&Sl[e],  pk4(sl));
        st8_sc(&PhA[e], pk4(ph));
        st8_sc(&PlA[e], pk4(pl));
        *(float4*)&PfA[e] = make_float4(p1[0], p1[1], p1[2], p1[3]);  // block-local
    }
    int gen = 0;
    gridbar(bar, ++gen);

    // ---- 4 NS iterations, depth-2, all blocks busy every segment ----
    u16 *ph = PhA, *pl = PlA, *qh = PhB, *ql = PlB;
    float *pf = PfA, *qf = PfB;
    const int i0a = ((b & 63) >> 3) << 6, j0a = (b & 7) << 6;   // 64x64
    for (int it = 0; it < 4; ++it) {
        if (b < 64)
            mm_bk64<64>(ph, pl, ph, pl, i0a, j0a, 1.f, nullptr, 0.f,
                        nullptr, T2h, T2l, S);                  // T2 = P*P
        else
            mm_bk64<64>(ph, pl, Sh, Sl, i0a, j0a, 1.f, nullptr, 0.f,
                        nullptr, Wh, Wl, S);                    // W = P*Sigma
        gridbar(bar, ++gen);
        mm_bk64<32>(T2h, T2l, Wh, Wl, R0, C0, -0.5f, pf, 1.5f,
                    qf, qh, ql, S);                             // Pn = 1.5P - .5*T2*W
        gridbar(bar, ++gen);
        { u16* x = ph; ph = qh; qh = x; }
        { u16* x = pl; pl = ql; ql = x; }
        { float* x = pf; pf = qf; qf = x; }
    }
    // 4 swaps -> final P in PfA/PhA (pf == PfA, ph == PhA here)

    // ---- wmm: own-tile partial, atomic combine (wmmv pre-zeroed) ----
    {
        const int row = R0 + (t >> 3);
        const int jb  = C0 + ((t & 7) << 3);
        float s = 0.f;
#pragma unroll
        for (int jj = 0; jj < 8; ++jj)
            s += pf[((size_t)row << 9) + jb + jj] * meanL[jb + jj];
        s += __shfl_xor(s, 1);
        s += __shfl_xor(s, 2);
        s += __shfl_xor(s, 4);
        if ((t & 7) == 0) atomicAdd(&wmmv[row], s * sr);
    }
}

// ---------------------------------------------------------------------------
// K6: whiten via bf16 MFMA.  [round-5 verified]
// ---------------------------------------------------------------------------
__global__ __launch_bounds__(256) void whiten_mfma(const u16* __restrict__ Xt,
                                                   const u16* __restrict__ Pbf,
                                                   const float* __restrict__ wmm,
                                                   const float* __restrict__ scal,
                                                   float* __restrict__ out) {
    const int id  = blockIdx.x;
    const int m   = (id >> 3) & 3;                 // c'-tile (member)
    const int grp = (id & 7) + ((id >> 5) << 3);   // 0..511
    const int c0  = m << 7;
    const int h0  = (grp & 7) << 7;
    const int n   = grp >> 3;
    const int t   = threadIdx.x;
    const int w   = t >> 6, l = t & 63;

    __shared__ char smem[128 * 68 * 4];            // 34816 B
    u16* AsB = (u16*)smem;                         // [2][4096]
    u16* BsB = AsB + 8192;                         // [2][4096]
    float* Ep = (float*)smem;                      // epilogue tile [128][68]

    floatx4 acc[4][4];
#pragma unroll
    for (int mi = 0; mi < 4; ++mi)
#pragma unroll
        for (int ni = 0; ni < 4; ++ni) acc[mi][ni] = (floatx4){0.f, 0.f, 0.f, 0.f};

    const int lr = l >> 2;
    const int lc = (l & 3) << 3;
    const int wm = w >> 1, wn = w & 1;
    const int fm = l & 15, fq = l >> 4;

    const u16* Xn = Xt + (size_t)n * CHW;

    auto issue = [&](int k, int bb) {
#pragma unroll
        for (int p = 0; p < 2; ++p) {
            const int g   = w * 2 + p;
            const int row = g * 16 + lr;
            gld_lds16(Xn  + (size_t)(h0 + row) * Cc + (k << 5) + lc, &AsB[bb * 4096 + g * 512]);
            gld_lds16(Pbf + (size_t)(c0 + row) * Cc + (k << 5) + lc, &BsB[bb * 4096 + g * 512]);
        }
    };

    issue(0, 0);
    __syncthreads();
    for (int k = 0; k < 16; ++k) {
        if (k < 15) issue(k + 1, (k + 1) & 1);
        const int bb = k & 1;
        short8 a[4], b[4];
#pragma unroll
        for (int mi = 0; mi < 4; ++mi)
            a[mi] = *(const short8*)&AsB[bb * 4096 + (wm * 64 + mi * 16 + fm) * 32 + fq * 8];
#pragma unroll
        for (int ni = 0; ni < 4; ++ni)
            b[ni] = *(const short8*)&BsB[bb * 4096 + (wn * 64 + ni * 16 + fm) * 32 + fq * 8];
#pragma unroll
        for (int mi = 0; mi < 4; ++mi)
#pragma unroll
            for (int ni = 0; ni < 4; ++ni)
                acc[mi][ni] = __builtin_amdgcn_mfma_f32_16x16x32_bf16(
                    a[mi], b[ni], acc[mi][ni], 0, 0, 0);
        __syncthreads();
    }

    const float sr = scal[1];
    float wv[4];
#pragma unroll
    for (int ni = 0; ni < 4; ++ni) wv[ni] = wmm[c0 + wn * 64 + ni * 16 + fm];
    float* outn = out + (size_t)n * CHW;

#pragma unroll
    for (int mp = 0; mp < 2; ++mp) {
        __syncthreads();
#pragma unroll
        for (int p = 0; p < 2; ++p) {
            const int mi = mp * 2 + p;
#pragma unroll
            for (int ni = 0; ni < 4; ++ni) {
                const int row  = wn * 64 + ni * 16 + fm;
                const int slot = wm * 32 + p * 16 + fq * 4;
                floatx4 v = acc[mi][ni] * sr - wv[ni];
                *(floatx4*)&Ep[row * 68 + slot] = v;
            }
        }
        __syncthreads();
#pragma unroll
        for (int jj = 0; jj < 8; ++jj) {
            const int idx = jj * 256 + t;          // 2048 float4
            const int row = idx >> 4;
            const int s4  = (idx & 15) << 2;       // 0..60
            const int wmr = s4 >> 5;
            const int within = s4 & 31;
            float4 v = *(const float4*)&Ep[row * 68 + s4];
            *(float4*)&outn[(size_t)(c0 + row) * HWs + h0 + wmr * 64 + mp * 32 + within] = v;
        }
    }
}

// ---------------------------------------------------------------------------
// Fallback fp32 kernels (used only if ws too small)
// ---------------------------------------------------------------------------
__global__ __launch_bounds__(256) void mean_kernel(const float* __restrict__ X,
                                                   float* __restrict__ mean) {
    const int c = blockIdx.x;
    const int t = threadIdx.x;
    float s = 0.f;
    for (int n = 0; n < Nn; ++n) {
        const float4* p = (const float4*)(X + (size_t)n * CHW + (size_t)c * HWs);
        float4 v = p[t];
        s += v.x + v.y + v.z + v.w;
    }
    __shared__ float red[256];
    red[t] = s;
    __syncthreads();
    for (int o = 128; o > 0; o >>= 1) {
        if (t < o) red[t] += red[t + o];
        __syncthreads();
    }
    if (t == 0) mean[c] = red[0] * (1.0f / Mm);
}

__global__ __launch_bounds__(256) void trace_fb(const float* __restrict__ G,
                                                const float* __restrict__ mean,
                                                float* __restrict__ scal) {
    const int t = threadIdx.x;
    float s = 0.f;
    for (int i = t; i < Cc; i += 256)
        s += G[(size_t)i * Cc + i] * (1.0f / Mm) - mean[i] * mean[i];
    __shared__ float red[256];
    red[t] = s;
    __syncthreads();
    for (int o = 128; o > 0; o >>= 1) {
        if (t < o) red[t] += red[t + o];
        __syncthreads();
    }
    if (t == 0) {
        const float tr  = red[0] + (float)Cc * EPSC;
        const float rtr = 1.0f / tr;
        scal[0] = rtr;
        scal[1] = sqrtf(rtr);
    }
}

__global__ __launch_bounds__(256) void gram_kernel(const float* __restrict__ X,
                                                   float* __restrict__ G) {
    const int ti = blockIdx.x >> 3, tj = blockIdx.x & 7;
    const int i0 = ti << 6, j0 = tj << 6;
    const int n0 = blockIdx.y << 3;
    const int t  = threadIdx.x;
    const int tx = t & 15, ty = t >> 4;
    __shared__ float As[64][33];
    __shared__ float Bs[64][33];
    float acc[4][4] = {};
    const int lc = t & 31;
    const int lr0 = t >> 5;
    for (int n = n0; n < n0 + 8; ++n) {
        const float* Xn = X + (size_t)n * CHW;
        for (int hw0 = 0; hw0 < HWs; hw0 += 32) {
#pragma unroll
            for (int r = 0; r < 8; ++r) {
                const int row = lr0 + (r << 3);
                As[row][lc] = Xn[(size_t)(i0 + row) * HWs + hw0 + lc];
                Bs[row][lc] = Xn[(size_t)(j0 + row) * HWs + hw0 + lc];
            }
            __syncthreads();
#pragma unroll
            for (int k = 0; k < 32; ++k) {
                float a[4], b[4];
#pragma unroll
                for (int r = 0; r < 4; ++r) a[r] = As[(ty << 2) + r][k];
#pragma unroll
                for (int cn = 0; cn < 4; ++cn) b[cn] = Bs[(tx << 2) + cn][k];
#pragma unroll
                for (int r = 0; r < 4; ++r)
#pragma unroll
                    for (int cn = 0; cn < 4; ++cn) acc[r][cn] += a[r] * b[cn];
            }
            __syncthreads();
        }
    }
#pragma unroll
    for (int r = 0; r < 4; ++r)
#pragma unroll
        for (int cn = 0; cn < 4; ++cn)
            atomicAdd(&G[(size_t)(i0 + (ty << 2) + r) * Cc + j0 + (tx << 2) + cn],
                      acc[r][cn]);
}

__global__ __launch_bounds__(256) void sigman_full_kernel(const float* __restrict__ G,
                                                          const float* __restrict__ mean,
                                                          const float* __restrict__ scal,
                                                          float* __restrict__ S,
                                                          float* __restrict__ P) {
    const int e = blockIdx.x * 256 + threadIdx.x;
    const int i = e >> 9, j = e & 511;
    const float rtr = scal[0];
    float sig = G[e] * (1.0f / Mm) - mean[i] * mean[j];
    if (i == j) sig += EPSC;
    S[e] = sig * rtr;
    P[e] = (i == j) ? 1.f : 0.f;
}

__global__ __launch_bounds__(256) void mm512_kernel(const float* __restrict__ A,
                                                    const float* __restrict__ B,
                                                    float* __restrict__ C,
                                                    float alpha,
                                                    const float* __restrict__ D,
                                                    float beta) {
    const int ti = blockIdx.x >> 3, tj = blockIdx.x & 7;
    const int i0 = ti << 6, j0 = tj << 6;
    const int t  = threadIdx.x;
    const int tx = t & 15, ty = t >> 4;
    __shared__ float As[64][33];
    __shared__ float Bs[32][65];
    float acc[4][4] = {};
    const int lcA = t & 31, lrA = t >> 5;
    const int lcB = t & 63, lrB = t >> 6;
    for (int k0 = 0; k0 < 512; k0 += 32) {
#pragma unroll
        for (int r = 0; r < 8; ++r) {
            const int row = lrA + (r << 3);
            As[row][lcA] = A[(size_t)(i0 + row) * 512 + k0 + lcA];
        }
#pragma unroll
        for (int r = 0; r < 8; ++r) {
            const int row = lrB + (r << 2);
            Bs[row][lcB] = B[(size_t)(k0 + row) * 512 + j0 + lcB];
        }
        __syncthreads();
#pragma unroll
        for (int k = 0; k < 32; ++k) {
            float a[4], b[4];
#pragma unroll
            for (int r = 0; r < 4; ++r) a[r] = As[(ty << 2) + r][k];
#pragma unroll
            for (int cn = 0; cn < 4; ++cn) b[cn] = Bs[k][(tx << 2) + cn];
#pragma unroll
            for (int r = 0; r < 4; ++r)
#pragma unroll
                for (int cn = 0; cn < 4; ++cn) acc[r][cn] += a[r] * b[cn];
        }
        __syncthreads();
    }
#pragma unroll
    for (int r = 0; r < 4; ++r) {
        const size_t idx = (size_t)(i0 + (ty << 2) + r) * 512 + j0 + (tx << 2);
        float4 v;
        v.x = alpha * acc[r][0];
        v.y = alpha * acc[r][1];
        v.z = alpha * acc[r][2];
        v.w = alpha * acc[r][3];
        if (D) {
            const float4 d = *(const float4*)(D + idx);
            v.x += beta * d.x; v.y += beta * d.y; v.z += beta * d.z; v.w += beta * d.w;
        }
        *(float4*)(C + idx) = v;
    }
}

__global__ __launch_bounds__(128) void wmm_kernel(const float* __restrict__ P,
                                                  const float* __restrict__ mean,
                                                  const float* __restrict__ scal,
                                                  float* __restrict__ wmm) {
    const int c = blockIdx.x, t = threadIdx.x;
    float s = 0.f;
    for (int j = t; j < Cc; j += 128) s += P[(size_t)c * Cc + j] * mean[j];
    __shared__ float red[128];
    red[t] = s;
    __syncthreads();
    for (int o = 64; o > 0; o >>= 1) {
        if (t < o) red[t] += red[t + o];
        __syncthreads();
    }
    if (t == 0) wmm[c] = red[0] * scal[1];
}

__global__ __launch_bounds__(256) void whiten_kernel(const float* __restrict__ X,
                                                     const float* __restrict__ P,
                                                     const float* __restrict__ wmm,
                                                     const float* __restrict__ scal,
                                                     float* __restrict__ out) {
    const int c0 = blockIdx.x << 6;
    const int h0 = blockIdx.y << 6;
    const int n  = blockIdx.z;
    const int t  = threadIdx.x;
    const int tx = t & 15, ty = t >> 4;
    __shared__ float Ps[64][33];
    __shared__ float Xs[32][65];
    float acc[4][4] = {};
    const int lcA = t & 31, lrA = t >> 5;
    const int lcB = t & 63, lrB = t >> 6;
    const float* Xn = X + (size_t)n * CHW;
    for (int k0 = 0; k0 < 512; k0 += 32) {
#pragma unroll
        for (int r = 0; r < 8; ++r) {
            const int row = lrA + (r << 3);
            Ps[row][lcA] = P[(size_t)(c0 + row) * 512 + k0 + lcA];
        }
#pragma unroll
        for (int r = 0; r < 8; ++r) {
            const int row = lrB + (r << 2);
            Xs[row][lcB] = Xn[(size_t)(k0 + row) * HWs + h0 + lcB];
        }
        __syncthreads();
#pragma unroll
        for (int k = 0; k < 32; ++k) {
            float a[4], b[4];
#pragma unroll
            for (int r = 0; r < 4; ++r) a[r] = Ps[(ty << 2) + r][k];
#pragma unroll
            for (int cn = 0; cn < 4; ++cn) b[cn] = Xs[k][(tx << 2) + cn];
#pragma unroll
            for (int r = 0; r < 4; ++r)
#pragma unroll
                for (int cn = 0; cn < 4; ++cn) acc[r][cn] += a[r] * b[cn];
        }
        __syncthreads();
    }
    const float sr = scal[1];
#pragma unroll
    for (int r = 0; r < 4; ++r) {
        const int c = c0 + (ty << 2) + r;
        const float wv = wmm[c];
        float4 v;
        v.x = sr * acc[r][0] - wv;
        v.y = sr * acc[r][1] - wv;
        v.z = sr * acc[r][2] - wv;
        v.w = sr * acc[r][3] - wv;
        *(float4*)(out + (size_t)n * CHW + (size_t)c * HWs + h0 + (tx << 2)) = v;
    }
}

// ---------------------------------------------------------------------------
extern "C" void kernel_launch(void* const* d_in, const int* in_sizes, int n_in,
                              void* d_out, int out_size, void* d_ws, size_t ws_size,
                              hipStream_t stream) {
    const float* X = (const float*)d_in[0];
    float* out     = (float*)d_out;

    const size_t NU16 = 33554432;   // CHW*Nn
    const size_t NM   = 262144;     // 512*512
    const size_t NEED = NU16 * 2 * 2                              // Xbf + Xt
                      + NM * 10 * 2                               // 10 bf16 512x512 mats
                      + (NM + 8192 + 32 + 512 + 512 + 2 * NM) * 4;// G,meanP,scal+bar,mean,wmm,PfA/B

    if (ws_size >= NEED) {
        u16* Xbf = (u16*)d_ws;
        u16* Xt  = Xbf + NU16;
        u16* Sh  = Xt  + NU16;
        u16* Sl  = Sh + NM;
        u16* PhA = Sl + NM;
        u16* PlA = PhA + NM;
        u16* PhB = PlA + NM;
        u16* PlB = PhB + NM;
        u16* T2h = PlB + NM;
        u16* T2l = T2h + NM;
        u16* Wh  = T2l + NM;
        u16* Wl  = Wh + NM;
        float* G     = (float*)(Wl + NM);
        float* meanP = G + NM;               // 16*512 partials
        float* scal  = meanP + 8192;         // 16 floats
        int*   bar   = (int*)(scal + 16);    // 16 ints (grid barrier)
        float* mean  = (float*)(bar + 16);   // 512 (unused in fast path)
        float* wmm   = mean + 512;           // 512 (atomic-combined -> must be zeroed)
        float* PfA   = wmm + 512;            // 262144
        float* PfB   = PfA + NM;             // 262144

        // zero G + meanP + scal + bar + mean + wmm in one memset (contiguous)
        hipMemsetAsync(G, 0, (NM + 8192 + 32 + 1024) * sizeof(float), stream);
        convert_transpose<<<dim3(16, 8, 64), 256, 0, stream>>>(X, Xbf, Xt, meanP);
        gram_mfma<<<640, 256, 0, stream>>>(Xbf, G);
        ns_chain<<<NBC, 256, 0, stream>>>(G, meanP, scal, bar, wmm,
                                          Sh, Sl, PhA, PlA, PhB, PlB,
                                          T2h, T2l, Wh, Wl, PfA, PfB);
        whiten_mfma<<<2048, 256, 0, stream>>>(Xt, PhA, wmm, scal, out);
    } else {
        // fallback: fp32 path (~6.3 MB ws)
        float* ws   = (float*)d_ws;
        float* mean = ws;
        float* wmm  = ws + 512;
        float* scal = ws + 1024;
        float* G    = ws + 2048;
        float* S    = G + 262144;
        float* Pa   = S + 262144;
        float* Pb   = Pa + 262144;
        float* P2   = Pb + 262144;
        float* P3   = P2 + 262144;

        mean_kernel<<<512, 256, 0, stream>>>(X, mean);
        hipMemsetAsync(G, 0, sizeof(float) * 262144, stream);
        gram_kernel<<<dim3(64, 8), 256, 0, stream>>>(X, G);
        trace_fb<<<1, 256, 0, stream>>>(G, mean, scal);
        sigman_full_kernel<<<1024, 256, 0, stream>>>(G, mean, scal, S, Pa);

        float* P  = Pa;
        float* Pn = Pb;
        for (int it = 0; it < 5; ++it) {
            mm512_kernel<<<64, 256, 0, stream>>>(P, P, P2, 1.f, nullptr, 0.f);
            mm512_kernel<<<64, 256, 0, stream>>>(P2, P, P3, 1.f, nullptr, 0.f);
            mm512_kernel<<<64, 256, 0, stream>>>(P3, S, Pn, -0.5f, P, 1.5f);
            float* tmp = P; P = Pn; Pn = tmp;
        }

        wmm_kernel<<<512, 128, 0, stream>>>(P, mean, scal, wmm);
        whiten_kernel<<<dim3(8, 16, 64), 256, 0, stream>>>(X, P, wmm, scal, out);
    }
}

// Round 7
// 464.652 us; speedup vs baseline: 1.1278x; 1.0067x over previous
//
#include <hip/hip_runtime.h>
#include <math.h>

// Problem constants (X: [64, 512, 32, 32] fp32)
#define Nn   64
#define Cc   512
#define HWs  1024
#define CHW  (Cc * HWs)      // 524288
#define Mm   (Nn * HWs)      // 65536
#define EPSC 1e-5f
#define NBC  128             // ns_chain block count (grid barrier)

typedef unsigned int   u32;
typedef unsigned short u16;
typedef unsigned long long u64;
typedef __attribute__((ext_vector_type(8))) short  short8;   // 8 x bf16 = 4 VGPR
typedef __attribute__((ext_vector_type(4))) float  floatx4;

__device__ __forceinline__ u16 f2bf(float f) {
    u32 u = __float_as_uint(f);
    u += 0x7fff + ((u >> 16) & 1);   // RNE
    return (u16)(u >> 16);
}
__device__ __forceinline__ float bf2f(u16 h) {
    return __uint_as_float(((u32)h) << 16);
}

__device__ __forceinline__ void gld_lds16(const u16* g, u16* l) {
    // async global->LDS, 16B per lane; LDS dest = wave-uniform base + lane*16
    __builtin_amdgcn_global_load_lds(
        (const __attribute__((address_space(1))) u32*)g,
        (__attribute__((address_space(3))) u32*)l, 16, 0, 0);
}

// sc0|sc1 cache policy (gfx940+ CPol: SC0=1, NT=2, SC1=16): read/write the
// device coherence point, bypassing (and not polluting/invalidating) L1/L2.
#define AUX_SC 0x11

__device__ __forceinline__ void gld_lds16_sc(const u16* g, u16* l) {
    __builtin_amdgcn_global_load_lds(
        (const __attribute__((address_space(1))) u32*)g,
        (__attribute__((address_space(3))) u32*)l, 16, 0, AUX_SC);
}
// 8-byte coherent store (4 packed bf16)
__device__ __forceinline__ void st8_sc(u16* p, u64 pk) {
    asm volatile("global_store_dwordx2 %0, %1, off sc0 sc1"
                 :: "v"(p), "v"(pk) : "memory");
}
__device__ __forceinline__ u64 pk4(const u16* h) {
    return (u64)h[0] | ((u64)h[1] << 16) | ((u64)h[2] << 32) | ((u64)h[3] << 48);
}

// ---------------------------------------------------------------------------
// K0: fp32 -> bf16 convert (natural layout) + transposed copy Xt[n][hw][c]
//     + fused per-channel partial sums into meanP[16][512] (atomics).
// Grid (16 hw-tiles, 8 c-tiles, 64 n), 256 threads.   [round-0 verified]
// ---------------------------------------------------------------------------
__global__ __launch_bounds__(256) void convert_transpose(const float* __restrict__ X,
                                                         u16* __restrict__ Xbf,
                                                         u16* __restrict__ Xt,
                                                         float* __restrict__ meanP) {
    const int hT = blockIdx.x;
    const int h0 = hT << 6;
    const int c0 = blockIdx.y << 6;
    const int n  = blockIdx.z;
    const int t  = threadIdx.x;
    __shared__ u16   T[64][65];
    __shared__ float red[64][17];

    const float* Xn  = X   + (size_t)n * CHW;
    u16*         Xbn = Xbf + (size_t)n * CHW;
    u16*         Xtn = Xt  + (size_t)n * CHW;

    const int cl = t >> 4;          // 0..15
    const int h4 = (t & 15) << 2;   // 0,4,..,60
#pragma unroll
    for (int i = 0; i < 4; ++i) {
        const int c = cl + (i << 4);
        float4 v = *(const float4*)&Xn[(size_t)(c0 + c) * HWs + h0 + h4];
        red[c][t & 15] = v.x + v.y + v.z + v.w;
        u16 b0 = f2bf(v.x), b1 = f2bf(v.y), b2 = f2bf(v.z), b3 = f2bf(v.w);
        *(ushort4*)&Xbn[(size_t)(c0 + c) * HWs + h0 + h4] = make_ushort4(b0, b1, b2, b3);
        T[c][h4]     = b0;
        T[c][h4 + 1] = b1;
        T[c][h4 + 2] = b2;
        T[c][h4 + 3] = b3;
    }
    __syncthreads();
    const int hl = t >> 4;
    const int c4 = (t & 15) << 2;
#pragma unroll
    for (int i = 0; i < 4; ++i) {
        const int h = hl + (i << 4);
        ushort4 pk = make_ushort4(T[c4][h], T[c4 + 1][h], T[c4 + 2][h], T[c4 + 3][h]);
        *(ushort4*)&Xtn[(size_t)(h0 + h) * Cc + c0 + c4] = pk;
    }
    if (t < 64) {
        float s = 0.f;
#pragma unroll
        for (int j = 0; j < 16; ++j) s += red[t][j];
        atomicAdd(&meanP[hT * 512 + c0 + t], s);
    }
}

// ---------------------------------------------------------------------------
// K2: Gram via bf16 MFMA, upper-triangle 128x128 tiles, split-K over n-pairs.
// ROUND-7: back to 32 splits / 320 blocks (R5's 64 splits doubled the
// atomicAdd count to 10.5M and cost ~9us).  Pipelined flat 64-step loop
// (2 n x 32 hw-steps), single sync per step.  [fragment math round-0 verified]
// ---------------------------------------------------------------------------
__global__ __launch_bounds__(256) void gram_mfma(const u16* __restrict__ Xbf,
                                                 float* __restrict__ G) {
    static const int TI[10] = {0,0,0,0,1,1,1,2,2,3};
    static const int TJ[10] = {0,1,2,3,1,2,3,2,3,3};
    const int id = blockIdx.x;
    const int q  = id >> 3;
    const int x  = q % 10;                        // tile index
    const int y  = (id & 7) + ((q / 10) << 3);    // n-split 0..31
    const int i0 = TI[x] << 7;
    const int j0 = TJ[x] << 7;
    const int n0 = y << 1;
    const int t  = threadIdx.x;
    const int w  = t >> 6, l = t & 63;

    __shared__ u16 As[2][4096];
    __shared__ u16 Bs[2][4096];

    floatx4 acc[4][4];
#pragma unroll
    for (int mi = 0; mi < 4; ++mi)
#pragma unroll
        for (int ni = 0; ni < 4; ++ni) acc[mi][ni] = (floatx4){0.f, 0.f, 0.f, 0.f};

    const int lr = l >> 2;
    const int lc = (l & 3) << 3;
    const int wm = w >> 1, wn = w & 1;
    const int fm = l & 15, fq = l >> 4;

    auto issue = [&](int s, int bb) {
        const u16* Xn = Xbf + (size_t)(n0 + (s >> 5)) * CHW;
        const int hw  = (s & 31) << 5;
#pragma unroll
        for (int p = 0; p < 2; ++p) {
            const int g   = w * 2 + p;
            const int row = g * 16 + lr;
            gld_lds16(Xn + (size_t)(i0 + row) * HWs + hw + lc, &As[bb][g * 512]);
            gld_lds16(Xn + (size_t)(j0 + row) * HWs + hw + lc, &Bs[bb][g * 512]);
        }
    };

    issue(0, 0);
    __syncthreads();
    for (int s = 0; s < 64; ++s) {
        if (s < 63) issue(s + 1, (s + 1) & 1);
        const int bb = s & 1;
        short8 a[4], b[4];
#pragma unroll
        for (int mi = 0; mi < 4; ++mi)
            a[mi] = *(const short8*)&As[bb][(wm * 64 + mi * 16 + fm) * 32 + fq * 8];
#pragma unroll
        for (int ni = 0; ni < 4; ++ni)
            b[ni] = *(const short8*)&Bs[bb][(wn * 64 + ni * 16 + fm) * 32 + fq * 8];
#pragma unroll
        for (int mi = 0; mi < 4; ++mi)
#pragma unroll
            for (int ni = 0; ni < 4; ++ni)
                acc[mi][ni] = __builtin_amdgcn_mfma_f32_16x16x32_bf16(
                    a[mi], b[ni], acc[mi][ni], 0, 0, 0);
        __syncthreads();   // drains vmcnt: s+1 staged; all readers done with bb
    }
#pragma unroll
    for (int mi = 0; mi < 4; ++mi)
#pragma unroll
        for (int ni = 0; ni < 4; ++ni)
#pragma unroll
            for (int r = 0; r < 4; ++r) {
                const int gi = i0 + wm * 64 + mi * 16 + fq * 4 + r;
                const int gj = j0 + wn * 64 + ni * 16 + fm;
                atomicAdd(&G[(size_t)gi * Cc + gj], acc[mi][ni][r]);
            }
}

// ---------------------------------------------------------------------------
// Grid barrier [round-6 verified: fence-free; sc data + relaxed counter]
// ---------------------------------------------------------------------------
__device__ __forceinline__ void gridbar(int* bar, int gen) {
    asm volatile("s_waitcnt vmcnt(0)" ::: "memory");
    __syncthreads();
    if (threadIdx.x == 0) {
        __hip_atomic_fetch_add(bar, 1, __ATOMIC_RELAXED, __HIP_MEMORY_SCOPE_AGENT);
        while (__hip_atomic_load(bar, __ATOMIC_RELAXED, __HIP_MEMORY_SCOPE_AGENT) < gen * NBC)
            __builtin_amdgcn_s_sleep(1);
    }
    __syncthreads();
}

// ---------------------------------------------------------------------------
// 512-K split-bf16 MFMA matmul tile, MR x 64 output per block.
// [round-6 verified: BK=64 dbuf pipeline, sc staging, transposed sc C-write]
// ---------------------------------------------------------------------------
template <int MR>
__device__ __forceinline__ void mm_bk64(const u16* Ah, const u16* Al,
                                        const u16* Bh, const u16* Bl,
                                        int i0, int j0,
                                        float alpha, const float* D, float beta,
                                        float* Cf, u16* Ch, u16* Cl, u16* S) {
    const int t = threadIdx.x, w = t >> 6, l = t & 63;
    const int wm = w >> 1, wn = w & 1, fm = l & 15, fq = l >> 4;
    const int lr = l >> 2, lc = (l & 3) << 3;
    constexpr int MI     = MR / 32;
    constexpr int OFF_AL = MR * 64;
    constexpr int OFF_BH = 2 * MR * 64;
    constexpr int OFF_BL = 2 * MR * 64 + 4096;
    constexpr int BUFSZ  = 2 * MR * 64 + 8192;

    const u16* src  = (w == 0) ? Ah : (w == 1) ? Al : (w == 2) ? Bh : Bl;
    const int rbase = (w < 2) ? i0 : j0;
    const int R     = (w < 2) ? MR : 64;
    const int OFF   = (w == 0) ? 0 : (w == 1) ? OFF_AL : (w == 2) ? OFF_BH : OFF_BL;

    floatx4 acc[MI][2];
#pragma unroll
    for (int mi = 0; mi < MI; ++mi)
#pragma unroll
        for (int ni = 0; ni < 2; ++ni) acc[mi][ni] = (floatx4){0.f, 0.f, 0.f, 0.f};

    auto issue = [&](int c, int bb) {
        u16* dst = S + bb * BUFSZ + OFF;
        const u16* sp = src + (size_t)rbase * 512 + (c << 6);
#pragma unroll
        for (int s = 0; s < 2; ++s)
#pragma unroll 4
            for (int g = 0; g < (R >> 4); ++g)
                gld_lds16_sc(sp + (size_t)(g * 16 + lr) * 512 + s * 32 + lc,
                             dst + s * R * 32 + g * 512);
    };
    auto compute = [&](int bb) {
        const u16* base = S + bb * BUFSZ;
#pragma unroll
        for (int s = 0; s < 2; ++s) {
            short8 ah[MI], al[MI], bh[2], bl[2];
#pragma unroll
            for (int mi = 0; mi < MI; ++mi) {
                const int r = wm * (MR / 2) + mi * 16 + fm;
                const int o = s * MR * 32 + r * 32 + fq * 8;
                ah[mi] = *(const short8*)&base[o];
                al[mi] = *(const short8*)&base[OFF_AL + o];
            }
#pragma unroll
            for (int ni = 0; ni < 2; ++ni) {
                const int r = wn * 32 + ni * 16 + fm;
                const int o = s * 2048 + r * 32 + fq * 8;
                bh[ni] = *(const short8*)&base[OFF_BH + o];
                bl[ni] = *(const short8*)&base[OFF_BL + o];
            }
#pragma unroll
            for (int mi = 0; mi < MI; ++mi)
#pragma unroll
                for (int ni = 0; ni < 2; ++ni) {
                    acc[mi][ni] = __builtin_amdgcn_mfma_f32_16x16x32_bf16(ah[mi], bh[ni], acc[mi][ni], 0, 0, 0);
                    acc[mi][ni] = __builtin_amdgcn_mfma_f32_16x16x32_bf16(ah[mi], bl[ni], acc[mi][ni], 0, 0, 0);
                    acc[mi][ni] = __builtin_amdgcn_mfma_f32_16x16x32_bf16(al[mi], bh[ni], acc[mi][ni], 0, 0, 0);
                }
        }
    };

    issue(0, 0);
    __syncthreads();
    for (int c = 0; c < 8; ++c) {
        if (c < 7) issue(c + 1, (c + 1) & 1);
        compute(c & 1);
        __syncthreads();
    }

#pragma unroll
    for (int mi = 0; mi < MI; ++mi)
#pragma unroll
        for (int ni = 0; ni < 2; ++ni) {
            const int gib = i0 + wm * (MR / 2) + mi * 16 + fq * 4;   // row base
            const int gj  = j0 + wn * 32 + ni * 16 + fm;
            u16 h[4], lo[4];
#pragma unroll
            for (int r4 = 0; r4 < 4; ++r4) {
                float v = alpha * acc[mi][ni][r4];
                if (D) v += beta * D[(size_t)(gib + r4) * 512 + gj];
                if (Cf) Cf[(size_t)(gib + r4) * 512 + gj] = v;
                h[r4]  = f2bf(v);
                lo[r4] = f2bf(v - bf2f(h[r4]));
            }
            // symmetric matrix: store transposed row (gj, gib..gib+3), 8B packed
            st8_sc(&Ch[(size_t)gj * 512 + gib], pk4(h));
            st8_sc(&Cl[(size_t)gj * 512 + gib], pk4(lo));
        }
}

// ---------------------------------------------------------------------------
// ns_chain v4: 128 blocks, 9 grid barriers, fence-free coherence.
// [round-6 verified]
// ---------------------------------------------------------------------------
__global__ __launch_bounds__(256) void ns_chain(
    const float* G, const float* meanP, float* scal, int* bar, float* wmmv,
    u16* Sh, u16* Sl, u16* PhA, u16* PlA, u16* PhB, u16* PlB,
    u16* T2h, u16* T2l, u16* Wh, u16* Wl, float* PfA, float* PfB) {
    __shared__ u16   S[32768];    // 64 KB: 2 bufs x (2*64+128)*64
    __shared__ float meanL[512];
    __shared__ float redL[4];
    const int t = threadIdx.x, b = blockIdx.x;
    const int w = t >> 6, l = t & 63;

    // ---- setup: per-block redundant mean + trace (no grid barrier) ----
    float tp = 0.f;
#pragma unroll
    for (int cb = 0; cb < 2; ++cb) {
        const int c = t + (cb << 8);
        float s = 0.f;
#pragma unroll
        for (int q = 0; q < 16; ++q) s += meanP[(q << 9) + c];
        const float mc = s * (1.0f / Mm);
        meanL[c] = mc;
        tp += G[(size_t)c * 513] * (1.0f / Mm) - mc * mc;
    }
#pragma unroll
    for (int o = 32; o > 0; o >>= 1) tp += __shfl_xor(tp, o);
    if (l == 0) redL[w] = tp;
    __syncthreads();
    const float tr  = redL[0] + redL[1] + redL[2] + redL[3] + (float)Cc * EPSC;
    const float rtr = 1.0f / tr;
    const float sr  = sqrtf(rtr);
    if (b == 0 && t == 0) { scal[0] = rtr; scal[1] = sr; }

    // ---- sigma + P1, tile-matched distribution (rows R0..R0+31, cols C0..C0+63)
    const int R0 = (b >> 3) << 5;
    const int C0 = (b & 7) << 6;
#pragma unroll
    for (int k2 = 0; k2 < 2; ++k2) {
        const int idx4 = (k2 << 8) + t;          // 0..511
        const int i  = R0 + (idx4 >> 4);
        const int jb = C0 + ((idx4 & 15) << 2);
        float p1[4];
        u16 sh[4], sl[4], ph[4], pl[4];
#pragma unroll
        for (int u = 0; u < 4; ++u) {
            const int j = jb + u;
            const float g = (i <= j) ? G[((size_t)i << 9) + j] : G[((size_t)j << 9) + i];
            float sig = g * (1.0f / Mm) - meanL[i] * meanL[j];
            if (i == j) sig += EPSC;
            const float sN = sig * rtr;
            sh[u] = f2bf(sN);
            sl[u] = f2bf(sN - bf2f(sh[u]));
            p1[u] = ((i == j) ? 1.5f : 0.f) - 0.5f * sN;
            ph[u] = f2bf(p1[u]);
            pl[u] = f2bf(p1[u] - bf2f(ph[u]));
        }
        const size_t e = ((size_t)i << 9) + jb;
        st8_sc(&Sh[e],  pk4(sh));
        st8_sc(&Sl[e],  pk4(sl));
        st8_sc(&PhA[e], pk4(ph));
        st8_sc(&PlA[e], pk4(pl));
        *(float4*)&PfA[e] = make_float4(p1[0], p1[1], p1[2], p1[3]);  // block-local
    }
    int gen = 0;
    gridbar(bar, ++gen);

    // ---- 4 NS iterations, depth-2, all blocks busy every segment ----
    u16 *ph = PhA, *pl = PlA, *qh = PhB, *ql = PlB;
    float *pf = PfA, *qf = PfB;
    const int i0a = ((b & 63) >> 3) << 6, j0a = (b & 7) << 6;   // 64x64
    for (int it = 0; it < 4; ++it) {
        if (b < 64)
            mm_bk64<64>(ph, pl, ph, pl, i0a, j0a, 1.f, nullptr, 0.f,
                        nullptr, T2h, T2l, S);                  // T2 = P*P
        else
            mm_bk64<64>(ph, pl, Sh, Sl, i0a, j0a, 1.f, nullptr, 0.f,
                        nullptr, Wh, Wl, S);                    // W = P*Sigma
        gridbar(bar, ++gen);
        mm_bk64<32>(T2h, T2l, Wh, Wl, R0, C0, -0.5f, pf, 1.5f,
                    qf, qh, ql, S);                             // Pn = 1.5P - .5*T2*W
        gridbar(bar, ++gen);
        { u16* x = ph; ph = qh; qh = x; }
        { u16* x = pl; pl = ql; ql = x; }
        { float* x = pf; pf = qf; qf = x; }
    }
    // 4 swaps -> final P in PfA/PhA (pf == PfA, ph == PhA here)

    // ---- wmm: own-tile partial, atomic combine (wmmv pre-zeroed) ----
    {
        const int row = R0 + (t >> 3);
        const int jb  = C0 + ((t & 7) << 3);
        float s = 0.f;
#pragma unroll
        for (int jj = 0; jj < 8; ++jj)
            s += pf[((size_t)row << 9) + jb + jj] * meanL[jb + jj];
        s += __shfl_xor(s, 1);
        s += __shfl_xor(s, 2);
        s += __shfl_xor(s, 4);
        if ((t & 7) == 0) atomicAdd(&wmmv[row], s * sr);
    }
}

// ---------------------------------------------------------------------------
// K6: whiten via bf16 MFMA.  ROUND-7: 256x128 output tile per block (was
// 128x128) -> 1024 blocks, acc 8x4, MFMA:ds_read = 32:12 per sync (was 16:8),
// half the barriers per FLOP.  Pure 2x index-widening of the verified
// fragment pattern (wm spans 128 rows, mi 0..7, epilogue 4 rounds).
// XCD swizzle: 4 ids sharing grp read the same 256-hw Xt slice on one XCD.
// ---------------------------------------------------------------------------
__global__ __launch_bounds__(256) void whiten_mfma(const u16* __restrict__ Xt,
                                                   const u16* __restrict__ Pbf,
                                                   const float* __restrict__ wmm,
                                                   const float* __restrict__ scal,
                                                   float* __restrict__ out) {
    const int id  = blockIdx.x;
    const int m   = (id >> 3) & 3;                 // c'-tile (member)
    const int grp = (id & 7) + ((id >> 5) << 3);   // 0..255
    const int c0  = m << 7;
    const int h0  = (grp & 3) << 8;                // 4 hw-tiles of 256
    const int n   = grp >> 2;
    const int t   = threadIdx.x;
    const int w   = t >> 6, l = t & 63;

    __shared__ char smem[49152];                   // 48 KB
    u16* As = (u16*)smem;                          // [2][8192] : 256x32 each
    u16* Bs = As + 16384;                          // [2][4096] : 128x32 each
    float* Ep = (float*)smem;                      // epilogue tile [128][68]

    floatx4 acc[8][4];
#pragma unroll
    for (int mi = 0; mi < 8; ++mi)
#pragma unroll
        for (int ni = 0; ni < 4; ++ni) acc[mi][ni] = (floatx4){0.f, 0.f, 0.f, 0.f};

    const int lr = l >> 2;
    const int lc = (l & 3) << 3;
    const int wm = w >> 1, wn = w & 1;
    const int fm = l & 15, fq = l >> 4;

    const u16* Xn = Xt + (size_t)n * CHW;

    auto issue = [&](int k, int bb) {
        const int kk = k << 5;
#pragma unroll
        for (int gi = 0; gi < 4; ++gi) {           // A: 256 rows, wave covers 4 groups
            const int g = w * 4 + gi;
            gld_lds16(Xn + (size_t)(h0 + g * 16 + lr) * Cc + kk + lc,
                      &As[bb * 8192 + g * 512]);
        }
#pragma unroll
        for (int p = 0; p < 2; ++p) {              // B: 128 rows, wave covers 2 groups
            const int g = w * 2 + p;
            gld_lds16(Pbf + (size_t)(c0 + g * 16 + lr) * Cc + kk + lc,
                      &Bs[bb * 4096 + g * 512]);
        }
    };

    issue(0, 0);
    __syncthreads();
    for (int k = 0; k < 16; ++k) {
        if (k < 15) issue(k + 1, (k + 1) & 1);
        const int bb = k & 1;
        short8 a[8], b[4];
#pragma unroll
        for (int mi = 0; mi < 8; ++mi)
            a[mi] = *(const short8*)&As[bb * 8192 + (wm * 128 + mi * 16 + fm) * 32 + fq * 8];
#pragma unroll
        for (int ni = 0; ni < 4; ++ni)
            b[ni] = *(const short8*)&Bs[bb * 4096 + (wn * 64 + ni * 16 + fm) * 32 + fq * 8];
#pragma unroll
        for (int mi = 0; mi < 8; ++mi)
#pragma unroll
            for (int ni = 0; ni < 4; ++ni)
                acc[mi][ni] = __builtin_amdgcn_mfma_f32_16x16x32_bf16(
                    a[mi], b[ni], acc[mi][ni], 0, 0, 0);
        __syncthreads();
    }

    const float sr = scal[1];
    float wv[4];
#pragma unroll
    for (int ni = 0; ni < 4; ++ni) wv[ni] = wmm[c0 + wn * 64 + ni * 16 + fm];
    float* outn = out + (size_t)n * CHW;

    // Epilogue: 4 rounds of mi-pairs; each round stages [128 c'][64 hw] in LDS
    // (stride 68 -> conflict-free), then stores 256B-contiguous row segments.
#pragma unroll
    for (int mp = 0; mp < 4; ++mp) {
        __syncthreads();
#pragma unroll
        for (int p = 0; p < 2; ++p) {
            const int mi = mp * 2 + p;
#pragma unroll
            for (int ni = 0; ni < 4; ++ni) {
                const int row  = wn * 64 + ni * 16 + fm;    // c' (0..127)
                const int slot = wm * 32 + p * 16 + fq * 4; // hw-part (0..63)
                floatx4 v = acc[mi][ni] * sr - wv[ni];
                *(floatx4*)&Ep[row * 68 + slot] = v;
            }
        }
        __syncthreads();
#pragma unroll
        for (int jj = 0; jj < 8; ++jj) {
            const int idx = jj * 256 + t;          // 2048 float4
            const int row = idx >> 4;
            const int s4  = (idx & 15) << 2;       // 0..60
            const int wmr = s4 >> 5;
            const int within = s4 & 31;
            float4 v = *(const float4*)&Ep[row * 68 + s4];
            *(float4*)&outn[(size_t)(c0 + row) * HWs + h0 + wmr * 128 + mp * 32 + within] = v;
        }
    }
}

// ---------------------------------------------------------------------------
// Fallback fp32 kernels (used only if ws too small)
// ---------------------------------------------------------------------------
__global__ __launch_bounds__(256) void mean_kernel(const float* __restrict__ X,
                                                   float* __restrict__ mean) {
    const int c = blockIdx.x;
    const int t = threadIdx.x;
    float s = 0.f;
    for (int n = 0; n < Nn; ++n) {
        const float4* p = (const float4*)(X + (size_t)n * CHW + (size_t)c * HWs);
        float4 v = p[t];
        s += v.x + v.y + v.z + v.w;
    }
    __shared__ float red[256];
    red[t] = s;
    __syncthreads();
    for (int o = 128; o > 0; o >>= 1) {
        if (t < o) red[t] += red[t + o];
        __syncthreads();
    }
    if (t == 0) mean[c] = red[0] * (1.0f / Mm);
}

__global__ __launch_bounds__(256) void trace_fb(const float* __restrict__ G,
                                                const float* __restrict__ mean,
                                                float* __restrict__ scal) {
    const int t = threadIdx.x;
    float s = 0.f;
    for (int i = t; i < Cc; i += 256)
        s += G[(size_t)i * Cc + i] * (1.0f / Mm) - mean[i] * mean[i];
    __shared__ float red[256];
    red[t] = s;
    __syncthreads();
    for (int o = 128; o > 0; o >>= 1) {
        if (t < o) red[t] += red[t + o];
        __syncthreads();
    }
    if (t == 0) {
        const float tr  = red[0] + (float)Cc * EPSC;
        const float rtr = 1.0f / tr;
        scal[0] = rtr;
        scal[1] = sqrtf(rtr);
    }
}

__global__ __launch_bounds__(256) void gram_kernel(const float* __restrict__ X,
                                                   float* __restrict__ G) {
    const int ti = blockIdx.x >> 3, tj = blockIdx.x & 7;
    const int i0 = ti << 6, j0 = tj << 6;
    const int n0 = blockIdx.y << 3;
    const int t  = threadIdx.x;
    const int tx = t & 15, ty = t >> 4;
    __shared__ float As[64][33];
    __shared__ float Bs[64][33];
    float acc[4][4] = {};
    const int lc = t & 31;
    const int lr0 = t >> 5;
    for (int n = n0; n < n0 + 8; ++n) {
        const float* Xn = X + (size_t)n * CHW;
        for (int hw0 = 0; hw0 < HWs; hw0 += 32) {
#pragma unroll
            for (int r = 0; r < 8; ++r) {
                const int row = lr0 + (r << 3);
                As[row][lc] = Xn[(size_t)(i0 + row) * HWs + hw0 + lc];
                Bs[row][lc] = Xn[(size_t)(j0 + row) * HWs + hw0 + lc];
            }
            __syncthreads();
#pragma unroll
            for (int k = 0; k < 32; ++k) {
                float a[4], b[4];
#pragma unroll
                for (int r = 0; r < 4; ++r) a[r] = As[(ty << 2) + r][k];
#pragma unroll
                for (int cn = 0; cn < 4; ++cn) b[cn] = Bs[(tx << 2) + cn][k];
#pragma unroll
                for (int r = 0; r < 4; ++r)
#pragma unroll
                    for (int cn = 0; cn < 4; ++cn) acc[r][cn] += a[r] * b[cn];
            }
            __syncthreads();
        }
    }
#pragma unroll
    for (int r = 0; r < 4; ++r)
#pragma unroll
        for (int cn = 0; cn < 4; ++cn)
            atomicAdd(&G[(size_t)(i0 + (ty << 2) + r) * Cc + j0 + (tx << 2) + cn],
                      acc[r][cn]);
}

__global__ __launch_bounds__(256) void sigman_full_kernel(const float* __restrict__ G,
                                                          const float* __restrict__ mean,
                                                          const float* __restrict__ scal,
                                                          float* __restrict__ S,
                                                          float* __restrict__ P) {
    const int e = blockIdx.x * 256 + threadIdx.x;
    const int i = e >> 9, j = e & 511;
    const float rtr = scal[0];
    float sig = G[e] * (1.0f / Mm) - mean[i] * mean[j];
    if (i == j) sig += EPSC;
    S[e] = sig * rtr;
    P[e] = (i == j) ? 1.f : 0.f;
}

__global__ __launch_bounds__(256) void mm512_kernel(const float* __restrict__ A,
                                                    const float* __restrict__ B,
                                                    float* __restrict__ C,
                                                    float alpha,
                                                    const float* __restrict__ D,
                                                    float beta) {
    const int ti = blockIdx.x >> 3, tj = blockIdx.x & 7;
    const int i0 = ti << 6, j0 = tj << 6;
    const int t  = threadIdx.x;
    const int tx = t & 15, ty = t >> 4;
    __shared__ float As[64][33];
    __shared__ float Bs[32][65];
    float acc[4][4] = {};
    const int lcA = t & 31, lrA = t >> 5;
    const int lcB = t & 63, lrB = t >> 6;
    for (int k0 = 0; k0 < 512; k0 += 32) {
#pragma unroll
        for (int r = 0; r < 8; ++r) {
            const int row = lrA + (r << 3);
            As[row][lcA] = A[(size_t)(i0 + row) * 512 + k0 + lcA];
        }
#pragma unroll
        for (int r = 0; r < 8; ++r) {
            const int row = lrB + (r << 2);
            Bs[row][lcB] = B[(size_t)(k0 + row) * 512 + j0 + lcB];
        }
        __syncthreads();
#pragma unroll
        for (int k = 0; k < 32; ++k) {
            float a[4], b[4];
#pragma unroll
            for (int r = 0; r < 4; ++r) a[r] = As[(ty << 2) + r][k];
#pragma unroll
            for (int cn = 0; cn < 4; ++cn) b[cn] = Bs[k][(tx << 2) + cn];
#pragma unroll
            for (int r = 0; r < 4; ++r)
#pragma unroll
                for (int cn = 0; cn < 4; ++cn) acc[r][cn] += a[r] * b[cn];
        }
        __syncthreads();
    }
#pragma unroll
    for (int r = 0; r < 4; ++r) {
        const size_t idx = (size_t)(i0 + (ty << 2) + r) * 512 + j0 + (tx << 2);
        float4 v;
        v.x = alpha * acc[r][0];
        v.y = alpha * acc[r][1];
        v.z = alpha * acc[r][2];
        v.w = alpha * acc[r][3];
        if (D) {
            const float4 d = *(const float4*)(D + idx);
            v.x += beta * d.x; v.y += beta * d.y; v.z += beta * d.z; v.w += beta * d.w;
        }
        *(float4*)(C + idx) = v;
    }
}

__global__ __launch_bounds__(128) void wmm_kernel(const float* __restrict__ P,
                                                  const float* __restrict__ mean,
                                                  const float* __restrict__ scal,
                                                  float* __restrict__ wmm) {
    const int c = blockIdx.x, t = threadIdx.x;
    float s = 0.f;
    for (int j = t; j < Cc; j += 128) s += P[(size_t)c * Cc + j] * mean[j];
    __shared__ float red[128];
    red[t] = s;
    __syncthreads();
    for (int o = 64; o > 0; o >>= 1) {
        if (t < o) red[t] += red[t + o];
        __syncthreads();
    }
    if (t == 0) wmm[c] = red[0] * scal[1];
}

__global__ __launch_bounds__(256) void whiten_kernel(const float* __restrict__ X,
                                                     const float* __restrict__ P,
                                                     const float* __restrict__ wmm,
                                                     const float* __restrict__ scal,
                                                     float* __restrict__ out) {
    const int c0 = blockIdx.x << 6;
    const int h0 = blockIdx.y << 6;
    const int n  = blockIdx.z;
    const int t  = threadIdx.x;
    const int tx = t & 15, ty = t >> 4;
    __shared__ float Ps[64][33];
    __shared__ float Xs[32][65];
    float acc[4][4] = {};
    const int lcA = t & 31, lrA = t >> 5;
    const int lcB = t & 63, lrB = t >> 6;
    const float* Xn = X + (size_t)n * CHW;
    for (int k0 = 0; k0 < 512; k0 += 32) {
#pragma unroll
        for (int r = 0; r < 8; ++r) {
            const int row = lrA + (r << 3);
            Ps[row][lcA] = P[(size_t)(c0 + row) * 512 + k0 + lcA];
        }
#pragma unroll
        for (int r = 0; r < 8; ++r) {
            const int row = lrB + (r << 2);
            Xs[row][lcB] = Xn[(size_t)(k0 + row) * HWs + h0 + lcB];
        }
        __syncthreads();
#pragma unroll
        for (int k = 0; k < 32; ++k) {
            float a[4], b[4];
#pragma unroll
            for (int r = 0; r < 4; ++r) a[r] = Ps[(ty << 2) + r][k];
#pragma unroll
            for (int cn = 0; cn < 4; ++cn) b[cn] = Xs[k][(tx << 2) + cn];
#pragma unroll
            for (int r = 0; r < 4; ++r)
#pragma unroll
                for (int cn = 0; cn < 4; ++cn) acc[r][cn] += a[r] * b[cn];
        }
        __syncthreads();
    }
    const float sr = scal[1];
#pragma unroll
    for (int r = 0; r < 4; ++r) {
        const int c = c0 + (ty << 2) + r;
        const float wv = wmm[c];
        float4 v;
        v.x = sr * acc[r][0] - wv;
        v.y = sr * acc[r][1] - wv;
        v.z = sr * acc[r][2] - wv;
        v.w = sr * acc[r][3] - wv;
        *(float4*)(out + (size_t)n * CHW + (size_t)c * HWs + h0 + (tx << 2)) = v;
    }
}

// ---------------------------------------------------------------------------
extern "C" void kernel_launch(void* const* d_in, const int* in_sizes, int n_in,
                              void* d_out, int out_size, void* d_ws, size_t ws_size,
                              hipStream_t stream) {
    const float* X = (const float*)d_in[0];
    float* out     = (float*)d_out;

    const size_t NU16 = 33554432;   // CHW*Nn
    const size_t NM   = 262144;     // 512*512
    const size_t NEED = NU16 * 2 * 2                              // Xbf + Xt
                      + NM * 10 * 2                               // 10 bf16 512x512 mats
                      + (NM + 8192 + 32 + 512 + 512 + 2 * NM) * 4;// G,meanP,scal+bar,mean,wmm,PfA/B

    if (ws_size >= NEED) {
        u16* Xbf = (u16*)d_ws;
        u16* Xt  = Xbf + NU16;
        u16* Sh  = Xt  + NU16;
        u16* Sl  = Sh + NM;
        u16* PhA = Sl + NM;
        u16* PlA = PhA + NM;
        u16* PhB = PlA + NM;
        u16* PlB = PhB + NM;
        u16* T2h = PlB + NM;
        u16* T2l = T2h + NM;
        u16* Wh  = T2l + NM;
        u16* Wl  = Wh + NM;
        float* G     = (float*)(Wl + NM);
        float* meanP = G + NM;               // 16*512 partials
        float* scal  = meanP + 8192;         // 16 floats
        int*   bar   = (int*)(scal + 16);    // 16 ints (grid barrier)
        float* mean  = (float*)(bar + 16);   // 512 (unused in fast path)
        float* wmm   = mean + 512;           // 512 (atomic-combined -> must be zeroed)
        float* PfA   = wmm + 512;            // 262144
        float* PfB   = PfA + NM;             // 262144

        // zero G + meanP + scal + bar + mean + wmm in one memset (contiguous)
        hipMemsetAsync(G, 0, (NM + 8192 + 32 + 1024) * sizeof(float), stream);
        convert_transpose<<<dim3(16, 8, 64), 256, 0, stream>>>(X, Xbf, Xt, meanP);
        gram_mfma<<<320, 256, 0, stream>>>(Xbf, G);
        ns_chain<<<NBC, 256, 0, stream>>>(G, meanP, scal, bar, wmm,
                                          Sh, Sl, PhA, PlA, PhB, PlB,
                                          T2h, T2l, Wh, Wl, PfA, PfB);
        whiten_mfma<<<1024, 256, 0, stream>>>(Xt, PhA, wmm, scal, out);
    } else {
        // fallback: fp32 path (~6.3 MB ws)
        float* ws   = (float*)d_ws;
        float* mean = ws;
        float* wmm  = ws + 512;
        float* scal = ws + 1024;
        float* G    = ws + 2048;
        float* S    = G + 262144;
        float* Pa   = S + 262144;
        float* Pb   = Pa + 262144;
        float* P2   = Pb + 262144;
        float* P3   = P2 + 262144;

        mean_kernel<<<512, 256, 0, stream>>>(X, mean);
        hipMemsetAsync(G, 0, sizeof(float) * 262144, stream);
        gram_kernel<<<dim3(64, 8), 256, 0, stream>>>(X, G);
        trace_fb<<<1, 256, 0, stream>>>(G, mean, scal);
        sigman_full_kernel<<<1024, 256, 0, stream>>>(G, mean, scal, S, Pa);

        float* P  = Pa;
        float* Pn = Pb;
        for (int it = 0; it < 5; ++it) {
            mm512_kernel<<<64, 256, 0, stream>>>(P, P, P2, 1.f, nullptr, 0.f);
            mm512_kernel<<<64, 256, 0, stream>>>(P2, P, P3, 1.f, nullptr, 0.f);
            mm512_kernel<<<64, 256, 0, stream>>>(P3, S, Pn, -0.5f, P, 1.5f);
            float* tmp = P; P = Pn; Pn = tmp;
        }

        wmm_kernel<<<512, 128, 0, stream>>>(P, mean, scal, wmm);
        whiten_kernel<<<dim3(8, 16, 64), 256, 0, stream>>>(X, P, wmm, scal, out);
    }
}

// Round 8
// 458.676 us; speedup vs baseline: 1.1425x; 1.0130x over previous
//
#include <hip/hip_runtime.h>
#include <math.h>

// Problem constants (X: [64, 512, 32, 32] fp32)
#define Nn   64
#define Cc   512
#define HWs  1024
#define CHW  (Cc * HWs)      // 524288
#define Mm   (Nn * HWs)      // 65536
#define EPSC 1e-5f
#define NBC  128             // ns_chain block count (grid barrier)

typedef unsigned int   u32;
typedef unsigned short u16;
typedef unsigned long long u64;
typedef __attribute__((ext_vector_type(8))) short  short8;   // 8 x bf16 = 4 VGPR
typedef __attribute__((ext_vector_type(4))) float  floatx4;

__device__ __forceinline__ u16 f2bf(float f) {
    u32 u = __float_as_uint(f);
    u += 0x7fff + ((u >> 16) & 1);   // RNE
    return (u16)(u >> 16);
}
__device__ __forceinline__ float bf2f(u16 h) {
    return __uint_as_float(((u32)h) << 16);
}

__device__ __forceinline__ void gld_lds16(const u16* g, u16* l) {
    // async global->LDS, 16B per lane; LDS dest = wave-uniform base + lane*16
    __builtin_amdgcn_global_load_lds(
        (const __attribute__((address_space(1))) u32*)g,
        (__attribute__((address_space(3))) u32*)l, 16, 0, 0);
}

// sc0|sc1 cache policy (gfx940+ CPol: SC0=1, NT=2, SC1=16): read/write the
// device coherence point, bypassing (and not polluting/invalidating) L1/L2.
#define AUX_SC 0x11

__device__ __forceinline__ void gld_lds16_sc(const u16* g, u16* l) {
    __builtin_amdgcn_global_load_lds(
        (const __attribute__((address_space(1))) u32*)g,
        (__attribute__((address_space(3))) u32*)l, 16, 0, AUX_SC);
}
// 8-byte coherent store (4 packed bf16)
__device__ __forceinline__ void st8_sc(u16* p, u64 pk) {
    asm volatile("global_store_dwordx2 %0, %1, off sc0 sc1"
                 :: "v"(p), "v"(pk) : "memory");
}
__device__ __forceinline__ u64 pk4(const u16* h) {
    return (u64)h[0] | ((u64)h[1] << 16) | ((u64)h[2] << 32) | ((u64)h[3] << 48);
}

// Counted-vmcnt wait (T4): wait until <= N of this wave's VMEM ops remain.
#define WAITV(N) asm volatile("s_waitcnt vmcnt(" #N ")" ::: "memory")
#define RAWBAR() __builtin_amdgcn_s_barrier()

// ---------------------------------------------------------------------------
// K0: fp32 -> bf16 convert (natural layout) + transposed copy Xt[n][hw][c]
//     + fused per-channel partial sums into meanP[16][512] (atomics).
// Grid (16 hw-tiles, 8 c-tiles, 64 n), 256 threads.   [round-0 verified]
// ---------------------------------------------------------------------------
__global__ __launch_bounds__(256) void convert_transpose(const float* __restrict__ X,
                                                         u16* __restrict__ Xbf,
                                                         u16* __restrict__ Xt,
                                                         float* __restrict__ meanP) {
    const int hT = blockIdx.x;
    const int h0 = hT << 6;
    const int c0 = blockIdx.y << 6;
    const int n  = blockIdx.z;
    const int t  = threadIdx.x;
    __shared__ u16   T[64][65];
    __shared__ float red[64][17];

    const float* Xn  = X   + (size_t)n * CHW;
    u16*         Xbn = Xbf + (size_t)n * CHW;
    u16*         Xtn = Xt  + (size_t)n * CHW;

    const int cl = t >> 4;          // 0..15
    const int h4 = (t & 15) << 2;   // 0,4,..,60
#pragma unroll
    for (int i = 0; i < 4; ++i) {
        const int c = cl + (i << 4);
        float4 v = *(const float4*)&Xn[(size_t)(c0 + c) * HWs + h0 + h4];
        red[c][t & 15] = v.x + v.y + v.z + v.w;
        u16 b0 = f2bf(v.x), b1 = f2bf(v.y), b2 = f2bf(v.z), b3 = f2bf(v.w);
        *(ushort4*)&Xbn[(size_t)(c0 + c) * HWs + h0 + h4] = make_ushort4(b0, b1, b2, b3);
        T[c][h4]     = b0;
        T[c][h4 + 1] = b1;
        T[c][h4 + 2] = b2;
        T[c][h4 + 3] = b3;
    }
    __syncthreads();
    const int hl = t >> 4;
    const int c4 = (t & 15) << 2;
#pragma unroll
    for (int i = 0; i < 4; ++i) {
        const int h = hl + (i << 4);
        ushort4 pk = make_ushort4(T[c4][h], T[c4 + 1][h], T[c4 + 2][h], T[c4 + 3][h]);
        *(ushort4*)&Xtn[(size_t)(h0 + h) * Cc + c0 + c4] = pk;
    }
    if (t < 64) {
        float s = 0.f;
#pragma unroll
        for (int j = 0; j < 16; ++j) s += red[t][j];
        atomicAdd(&meanP[hT * 512 + c0 + t], s);
    }
}

// ---------------------------------------------------------------------------
// K2: Gram via bf16 MFMA, upper-triangle 128x128 tiles, split-K over n-pairs.
// ROUND-8: counted-vmcnt pipeline (T4).  Raw s_barrier (no implicit
// vmcnt(0) drain) + explicit vmcnt(4) [= this wave's loads/step] keeps the
// 2-step-deep prefetch in flight ACROSS barriers.  Fragment math unchanged.
// Per step: wait oldest-4 done -> barrier (buf ready) -> compute ->
// barrier (all readers done) -> issue s+2 into the freed buffer.
// ---------------------------------------------------------------------------
__global__ __launch_bounds__(256) void gram_mfma(const u16* __restrict__ Xbf,
                                                 float* __restrict__ G) {
    static const int TI[10] = {0,0,0,0,1,1,1,2,2,3};
    static const int TJ[10] = {0,1,2,3,1,2,3,2,3,3};
    const int id = blockIdx.x;
    const int q  = id >> 3;
    const int x  = q % 10;                        // tile index
    const int y  = (id & 7) + ((q / 10) << 3);    // n-split 0..31
    const int i0 = TI[x] << 7;
    const int j0 = TJ[x] << 7;
    const int n0 = y << 1;
    const int t  = threadIdx.x;
    const int w  = t >> 6, l = t & 63;

    __shared__ u16 As[2][4096];
    __shared__ u16 Bs[2][4096];

    floatx4 acc[4][4];
#pragma unroll
    for (int mi = 0; mi < 4; ++mi)
#pragma unroll
        for (int ni = 0; ni < 4; ++ni) acc[mi][ni] = (floatx4){0.f, 0.f, 0.f, 0.f};

    const int lr = l >> 2;
    const int lc = (l & 3) << 3;
    const int wm = w >> 1, wn = w & 1;
    const int fm = l & 15, fq = l >> 4;

    auto issue = [&](int s, int bb) {             // 4 gld per wave per step
        const u16* Xn = Xbf + (size_t)(n0 + (s >> 5)) * CHW;
        const int hw  = (s & 31) << 5;
#pragma unroll
        for (int p = 0; p < 2; ++p) {
            const int g   = w * 2 + p;
            const int row = g * 16 + lr;
            gld_lds16(Xn + (size_t)(i0 + row) * HWs + hw + lc, &As[bb][g * 512]);
            gld_lds16(Xn + (size_t)(j0 + row) * HWs + hw + lc, &Bs[bb][g * 512]);
        }
    };

    issue(0, 0);
    issue(1, 1);
    for (int s = 0; s < 64; ++s) {
        if (s < 63) WAITV(4); else WAITV(0);      // oldest step's 4 loads landed
        RAWBAR();                                 // buf[s&1] ready for all waves
        const int bb = s & 1;
        short8 a[4], b[4];
#pragma unroll
        for (int mi = 0; mi < 4; ++mi)
            a[mi] = *(const short8*)&As[bb][(wm * 64 + mi * 16 + fm) * 32 + fq * 8];
#pragma unroll
        for (int ni = 0; ni < 4; ++ni)
            b[ni] = *(const short8*)&Bs[bb][(wn * 64 + ni * 16 + fm) * 32 + fq * 8];
#pragma unroll
        for (int mi = 0; mi < 4; ++mi)
#pragma unroll
            for (int ni = 0; ni < 4; ++ni)
                acc[mi][ni] = __builtin_amdgcn_mfma_f32_16x16x32_bf16(
                    a[mi], b[ni], acc[mi][ni], 0, 0, 0);
        RAWBAR();                                 // all waves done reading bb
        if (s < 62) issue(s + 2, bb);             // refill freed buffer
    }
#pragma unroll
    for (int mi = 0; mi < 4; ++mi)
#pragma unroll
        for (int ni = 0; ni < 4; ++ni)
#pragma unroll
            for (int r = 0; r < 4; ++r) {
                const int gi = i0 + wm * 64 + mi * 16 + fq * 4 + r;
                const int gj = j0 + wn * 64 + ni * 16 + fm;
                atomicAdd(&G[(size_t)gi * Cc + gj], acc[mi][ni][r]);
            }
}

// ---------------------------------------------------------------------------
// Grid barrier [round-6 verified: fence-free; sc data + relaxed counter]
// ---------------------------------------------------------------------------
__device__ __forceinline__ void gridbar(int* bar, int gen) {
    asm volatile("s_waitcnt vmcnt(0)" ::: "memory");
    __syncthreads();
    if (threadIdx.x == 0) {
        __hip_atomic_fetch_add(bar, 1, __ATOMIC_RELAXED, __HIP_MEMORY_SCOPE_AGENT);
        while (__hip_atomic_load(bar, __ATOMIC_RELAXED, __HIP_MEMORY_SCOPE_AGENT) < gen * NBC)
            __builtin_amdgcn_s_sleep(1);
    }
    __syncthreads();
}

// ---------------------------------------------------------------------------
// 512-K split-bf16 MFMA matmul tile, MR x 64 output per block.
// [round-6 verified math]  ROUND-8: counted-vmcnt pipeline (see gram).
// Per-wave loads/chunk: MR=64 -> 8 all waves; MR=32 -> A-waves 4, B-waves 8.
// ---------------------------------------------------------------------------
template <int MR>
__device__ __forceinline__ void mm_bk64(const u16* Ah, const u16* Al,
                                        const u16* Bh, const u16* Bl,
                                        int i0, int j0,
                                        float alpha, const float* D, float beta,
                                        float* Cf, u16* Ch, u16* Cl, u16* S) {
    const int t = threadIdx.x, w = t >> 6, l = t & 63;
    const int wm = w >> 1, wn = w & 1, fm = l & 15, fq = l >> 4;
    const int lr = l >> 2, lc = (l & 3) << 3;
    constexpr int MI     = MR / 32;
    constexpr int OFF_AL = MR * 64;
    constexpr int OFF_BH = 2 * MR * 64;
    constexpr int OFF_BL = 2 * MR * 64 + 4096;
    constexpr int BUFSZ  = 2 * MR * 64 + 8192;

    const u16* src  = (w == 0) ? Ah : (w == 1) ? Al : (w == 2) ? Bh : Bl;
    const int rbase = (w < 2) ? i0 : j0;
    const int R     = (w < 2) ? MR : 64;
    const int OFF   = (w == 0) ? 0 : (w == 1) ? OFF_AL : (w == 2) ? OFF_BH : OFF_BL;

    floatx4 acc[MI][2];
#pragma unroll
    for (int mi = 0; mi < MI; ++mi)
#pragma unroll
        for (int ni = 0; ni < 2; ++ni) acc[mi][ni] = (floatx4){0.f, 0.f, 0.f, 0.f};

    auto issue = [&](int c, int bb) {
        u16* dst = S + bb * BUFSZ + OFF;
        const u16* sp = src + (size_t)rbase * 512 + (c << 6);
#pragma unroll
        for (int s = 0; s < 2; ++s)
#pragma unroll 4
            for (int g = 0; g < (R >> 4); ++g)
                gld_lds16_sc(sp + (size_t)(g * 16 + lr) * 512 + s * 32 + lc,
                             dst + s * R * 32 + g * 512);
    };
    auto waitL = [&](bool last) {
        if (last) { WAITV(0); return; }
        if (MR == 64) { WAITV(8); }
        else if (w < 2) { WAITV(4); } else { WAITV(8); }
    };
    auto compute = [&](int bb) {
        const u16* base = S + bb * BUFSZ;
#pragma unroll
        for (int s = 0; s < 2; ++s) {
            short8 ah[MI], al[MI], bh[2], bl[2];
#pragma unroll
            for (int mi = 0; mi < MI; ++mi) {
                const int r = wm * (MR / 2) + mi * 16 + fm;
                const int o = s * MR * 32 + r * 32 + fq * 8;
                ah[mi] = *(const short8*)&base[o];
                al[mi] = *(const short8*)&base[OFF_AL + o];
            }
#pragma unroll
            for (int ni = 0; ni < 2; ++ni) {
                const int r = wn * 32 + ni * 16 + fm;
                const int o = s * 2048 + r * 32 + fq * 8;
                bh[ni] = *(const short8*)&base[OFF_BH + o];
                bl[ni] = *(const short8*)&base[OFF_BL + o];
            }
#pragma unroll
            for (int mi = 0; mi < MI; ++mi)
#pragma unroll
                for (int ni = 0; ni < 2; ++ni) {
                    acc[mi][ni] = __builtin_amdgcn_mfma_f32_16x16x32_bf16(ah[mi], bh[ni], acc[mi][ni], 0, 0, 0);
                    acc[mi][ni] = __builtin_amdgcn_mfma_f32_16x16x32_bf16(ah[mi], bl[ni], acc[mi][ni], 0, 0, 0);
                    acc[mi][ni] = __builtin_amdgcn_mfma_f32_16x16x32_bf16(al[mi], bh[ni], acc[mi][ni], 0, 0, 0);
                }
        }
    };

    issue(0, 0);
    issue(1, 1);
    for (int c = 0; c < 8; ++c) {
        waitL(c == 7);
        RAWBAR();
        compute(c & 1);
        RAWBAR();
        if (c < 6) issue(c + 2, c & 1);
    }

#pragma unroll
    for (int mi = 0; mi < MI; ++mi)
#pragma unroll
        for (int ni = 0; ni < 2; ++ni) {
            const int gib = i0 + wm * (MR / 2) + mi * 16 + fq * 4;   // row base
            const int gj  = j0 + wn * 32 + ni * 16 + fm;
            u16 h[4], lo[4];
#pragma unroll
            for (int r4 = 0; r4 < 4; ++r4) {
                float v = alpha * acc[mi][ni][r4];
                if (D) v += beta * D[(size_t)(gib + r4) * 512 + gj];
                if (Cf) Cf[(size_t)(gib + r4) * 512 + gj] = v;
                h[r4]  = f2bf(v);
                lo[r4] = f2bf(v - bf2f(h[r4]));
            }
            // symmetric matrix: store transposed row (gj, gib..gib+3), 8B packed
            st8_sc(&Ch[(size_t)gj * 512 + gib], pk4(h));
            st8_sc(&Cl[(size_t)gj * 512 + gib], pk4(lo));
        }
}

// ---------------------------------------------------------------------------
// ns_chain v4: 128 blocks, 9 grid barriers, fence-free coherence.
// [round-6 verified; mm_bk64 internals now counted-vmcnt pipelined]
// ---------------------------------------------------------------------------
__global__ __launch_bounds__(256) void ns_chain(
    const float* G, const float* meanP, float* scal, int* bar, float* wmmv,
    u16* Sh, u16* Sl, u16* PhA, u16* PlA, u16* PhB, u16* PlB,
    u16* T2h, u16* T2l, u16* Wh, u16* Wl, float* PfA, float* PfB) {
    __shared__ u16   S[32768];    // 64 KB: 2 bufs x (2*64+128)*64
    __shared__ float meanL[512];
    __shared__ float redL[4];
    const int t = threadIdx.x, b = blockIdx.x;
    const int w = t >> 6, l = t & 63;

    // ---- setup: per-block redundant mean + trace (no grid barrier) ----
    float tp = 0.f;
#pragma unroll
    for (int cb = 0; cb < 2; ++cb) {
        const int c = t + (cb << 8);
        float s = 0.f;
#pragma unroll
        for (int q = 0; q < 16; ++q) s += meanP[(q << 9) + c];
        const float mc = s * (1.0f / Mm);
        meanL[c] = mc;
        tp += G[(size_t)c * 513] * (1.0f / Mm) - mc * mc;
    }
#pragma unroll
    for (int o = 32; o > 0; o >>= 1) tp += __shfl_xor(tp, o);
    if (l == 0) redL[w] = tp;
    __syncthreads();
    const float tr  = redL[0] + redL[1] + redL[2] + redL[3] + (float)Cc * EPSC;
    const float rtr = 1.0f / tr;
    const float sr  = sqrtf(rtr);
    if (b == 0 && t == 0) { scal[0] = rtr; scal[1] = sr; }

    // ---- sigma + P1, tile-matched distribution (rows R0..R0+31, cols C0..C0+63)
    const int R0 = (b >> 3) << 5;
    const int C0 = (b & 7) << 6;
#pragma unroll
    for (int k2 = 0; k2 < 2; ++k2) {
        const int idx4 = (k2 << 8) + t;          // 0..511
        const int i  = R0 + (idx4 >> 4);
        const int jb = C0 + ((idx4 & 15) << 2);
        float p1[4];
        u16 sh[4], sl[4], ph[4], pl[4];
#pragma unroll
        for (int u = 0; u < 4; ++u) {
            const int j = jb + u;
            const float g = (i <= j) ? G[((size_t)i << 9) + j] : G[((size_t)j << 9) + i];
            float sig = g * (1.0f / Mm) - meanL[i] * meanL[j];
            if (i == j) sig += EPSC;
            const float sN = sig * rtr;
            sh[u] = f2bf(sN);
            sl[u] = f2bf(sN - bf2f(sh[u]));
            p1[u] = ((i == j) ? 1.5f : 0.f) - 0.5f * sN;
            ph[u] = f2bf(p1[u]);
            pl[u] = f2bf(p1[u] - bf2f(ph[u]));
        }
        const size_t e = ((size_t)i << 9) + jb;
        st8_sc(&Sh[e],  pk4(sh));
        st8_sc(&Sl[e],  pk4(sl));
        st8_sc(&PhA[e], pk4(ph));
        st8_sc(&PlA[e], pk4(pl));
        *(float4*)&PfA[e] = make_float4(p1[0], p1[1], p1[2], p1[3]);  // block-local
    }
    int gen = 0;
    gridbar(bar, ++gen);

    // ---- 4 NS iterations, depth-2, all blocks busy every segment ----
    u16 *ph = PhA, *pl = PlA, *qh = PhB, *ql = PlB;
    float *pf = PfA, *qf = PfB;
    const int i0a = ((b & 63) >> 3) << 6, j0a = (b & 7) << 6;   // 64x64
    for (int it = 0; it < 4; ++it) {
        if (b < 64)
            mm_bk64<64>(ph, pl, ph, pl, i0a, j0a, 1.f, nullptr, 0.f,
                        nullptr, T2h, T2l, S);                  // T2 = P*P
        else
            mm_bk64<64>(ph, pl, Sh, Sl, i0a, j0a, 1.f, nullptr, 0.f,
                        nullptr, Wh, Wl, S);                    // W = P*Sigma
        gridbar(bar, ++gen);
        mm_bk64<32>(T2h, T2l, Wh, Wl, R0, C0, -0.5f, pf, 1.5f,
                    qf, qh, ql, S);                             // Pn = 1.5P - .5*T2*W
        gridbar(bar, ++gen);
        { u16* x = ph; ph = qh; qh = x; }
        { u16* x = pl; pl = ql; ql = x; }
        { float* x = pf; pf = qf; qf = x; }
    }
    // 4 swaps -> final P in PfA/PhA (pf == PfA, ph == PhA here)

    // ---- wmm: own-tile partial, atomic combine (wmmv pre-zeroed) ----
    {
        const int row = R0 + (t >> 3);
        const int jb  = C0 + ((t & 7) << 3);
        float s = 0.f;
#pragma unroll
        for (int jj = 0; jj < 8; ++jj)
            s += pf[((size_t)row << 9) + jb + jj] * meanL[jb + jj];
        s += __shfl_xor(s, 1);
        s += __shfl_xor(s, 2);
        s += __shfl_xor(s, 4);
        if ((t & 7) == 0) atomicAdd(&wmmv[row], s * sr);
    }
}

// ---------------------------------------------------------------------------
// K6: whiten via bf16 MFMA, 256x128 tile (round-7).  ROUND-8: counted-vmcnt
// pipeline (6 loads per wave per step -> vmcnt(6) steady, vmcnt(0) last).
// Epilogue aliasing safe: last step drained to vmcnt(0) before compute.
// ---------------------------------------------------------------------------
__global__ __launch_bounds__(256) void whiten_mfma(const u16* __restrict__ Xt,
                                                   const u16* __restrict__ Pbf,
                                                   const float* __restrict__ wmm,
                                                   const float* __restrict__ scal,
                                                   float* __restrict__ out) {
    const int id  = blockIdx.x;
    const int m   = (id >> 3) & 3;                 // c'-tile (member)
    const int grp = (id & 7) + ((id >> 5) << 3);   // 0..255
    const int c0  = m << 7;
    const int h0  = (grp & 3) << 8;                // 4 hw-tiles of 256
    const int n   = grp >> 2;
    const int t   = threadIdx.x;
    const int w   = t >> 6, l = t & 63;

    __shared__ char smem[49152];                   // 48 KB
    u16* As = (u16*)smem;                          // [2][8192] : 256x32 each
    u16* Bs = As + 16384;                          // [2][4096] : 128x32 each
    float* Ep = (float*)smem;                      // epilogue tile [128][68]

    floatx4 acc[8][4];
#pragma unroll
    for (int mi = 0; mi < 8; ++mi)
#pragma unroll
        for (int ni = 0; ni < 4; ++ni) acc[mi][ni] = (floatx4){0.f, 0.f, 0.f, 0.f};

    const int lr = l >> 2;
    const int lc = (l & 3) << 3;
    const int wm = w >> 1, wn = w & 1;
    const int fm = l & 15, fq = l >> 4;

    const u16* Xn = Xt + (size_t)n * CHW;

    auto issue = [&](int k, int bb) {              // 6 gld per wave per step
        const int kk = k << 5;
#pragma unroll
        for (int gi = 0; gi < 4; ++gi) {           // A: 256 rows, wave covers 4 groups
            const int g = w * 4 + gi;
            gld_lds16(Xn + (size_t)(h0 + g * 16 + lr) * Cc + kk + lc,
                      &As[bb * 8192 + g * 512]);
        }
#pragma unroll
        for (int p = 0; p < 2; ++p) {              // B: 128 rows, wave covers 2 groups
            const int g = w * 2 + p;
            gld_lds16(Pbf + (size_t)(c0 + g * 16 + lr) * Cc + kk + lc,
                      &Bs[bb * 4096 + g * 512]);
        }
    };

    issue(0, 0);
    issue(1, 1);
    for (int k = 0; k < 16; ++k) {
        if (k < 15) WAITV(6); else WAITV(0);
        RAWBAR();
        const int bb = k & 1;
        short8 a[8], b[4];
#pragma unroll
        for (int mi = 0; mi < 8; ++mi)
            a[mi] = *(const short8*)&As[bb * 8192 + (wm * 128 + mi * 16 + fm) * 32 + fq * 8];
#pragma unroll
        for (int ni = 0; ni < 4; ++ni)
            b[ni] = *(const short8*)&Bs[bb * 4096 + (wn * 64 + ni * 16 + fm) * 32 + fq * 8];
#pragma unroll
        for (int mi = 0; mi < 8; ++mi)
#pragma unroll
            for (int ni = 0; ni < 4; ++ni)
                acc[mi][ni] = __builtin_amdgcn_mfma_f32_16x16x32_bf16(
                    a[mi], b[ni], acc[mi][ni], 0, 0, 0);
        RAWBAR();
        if (k < 14) issue(k + 2, bb);
    }

    const float sr = scal[1];
    float wv[4];
#pragma unroll
    for (int ni = 0; ni < 4; ++ni) wv[ni] = wmm[c0 + wn * 64 + ni * 16 + fm];
    float* outn = out + (size_t)n * CHW;

    // Epilogue: 4 rounds of mi-pairs; each round stages [128 c'][64 hw] in LDS
    // (stride 68 -> conflict-free), then stores 256B-contiguous row segments.
#pragma unroll
    for (int mp = 0; mp < 4; ++mp) {
        __syncthreads();
#pragma unroll
        for (int p = 0; p < 2; ++p) {
            const int mi = mp * 2 + p;
#pragma unroll
            for (int ni = 0; ni < 4; ++ni) {
                const int row  = wn * 64 + ni * 16 + fm;    // c' (0..127)
                const int slot = wm * 32 + p * 16 + fq * 4; // hw-part (0..63)
                floatx4 v = acc[mi][ni] * sr - wv[ni];
                *(floatx4*)&Ep[row * 68 + slot] = v;
            }
        }
        __syncthreads();
#pragma unroll
        for (int jj = 0; jj < 8; ++jj) {
            const int idx = jj * 256 + t;          // 2048 float4
            const int row = idx >> 4;
            const int s4  = (idx & 15) << 2;       // 0..60
            const int wmr = s4 >> 5;
            const int within = s4 & 31;
            float4 v = *(const float4*)&Ep[row * 68 + s4];
            *(float4*)&outn[(size_t)(c0 + row) * HWs + h0 + wmr * 128 + mp * 32 + within] = v;
        }
    }
}

// ---------------------------------------------------------------------------
// Fallback fp32 kernels (used only if ws too small)
// ---------------------------------------------------------------------------
__global__ __launch_bounds__(256) void mean_kernel(const float* __restrict__ X,
                                                   float* __restrict__ mean) {
    const int c = blockIdx.x;
    const int t = threadIdx.x;
    float s = 0.f;
    for (int n = 0; n < Nn; ++n) {
        const float4* p = (const float4*)(X + (size_t)n * CHW + (size_t)c * HWs);
        float4 v = p[t];
        s += v.x + v.y + v.z + v.w;
    }
    __shared__ float red[256];
    red[t] = s;
    __syncthreads();
    for (int o = 128; o > 0; o >>= 1) {
        if (t < o) red[t] += red[t + o];
        __syncthreads();
    }
    if (t == 0) mean[c] = red[0] * (1.0f / Mm);
}

__global__ __launch_bounds__(256) void trace_fb(const float* __restrict__ G,
                                                const float* __restrict__ mean,
                                                float* __restrict__ scal) {
    const int t = threadIdx.x;
    float s = 0.f;
    for (int i = t; i < Cc; i += 256)
        s += G[(size_t)i * Cc + i] * (1.0f / Mm) - mean[i] * mean[i];
    __shared__ float red[256];
    red[t] = s;
    __syncthreads();
    for (int o = 128; o > 0; o >>= 1) {
        if (t < o) red[t] += red[t + o];
        __syncthreads();
    }
    if (t == 0) {
        const float tr  = red[0] + (float)Cc * EPSC;
        const float rtr = 1.0f / tr;
        scal[0] = rtr;
        scal[1] = sqrtf(rtr);
    }
}

__global__ __launch_bounds__(256) void gram_kernel(const float* __restrict__ X,
                                                   float* __restrict__ G) {
    const int ti = blockIdx.x >> 3, tj = blockIdx.x & 7;
    const int i0 = ti << 6, j0 = tj << 6;
    const int n0 = blockIdx.y << 3;
    const int t  = threadIdx.x;
    const int tx = t & 15, ty = t >> 4;
    __shared__ float As[64][33];
    __shared__ float Bs[64][33];
    float acc[4][4] = {};
    const int lc = t & 31;
    const int lr0 = t >> 5;
    for (int n = n0; n < n0 + 8; ++n) {
        const float* Xn = X + (size_t)n * CHW;
        for (int hw0 = 0; hw0 < HWs; hw0 += 32) {
#pragma unroll
            for (int r = 0; r < 8; ++r) {
                const int row = lr0 + (r << 3);
                As[row][lc] = Xn[(size_t)(i0 + row) * HWs + hw0 + lc];
                Bs[row][lc] = Xn[(size_t)(j0 + row) * HWs + hw0 + lc];
            }
            __syncthreads();
#pragma unroll
            for (int k = 0; k < 32; ++k) {
                float a[4], b[4];
#pragma unroll
                for (int r = 0; r < 4; ++r) a[r] = As[(ty << 2) + r][k];
#pragma unroll
                for (int cn = 0; cn < 4; ++cn) b[cn] = Bs[(tx << 2) + cn][k];
#pragma unroll
                for (int r = 0; r < 4; ++r)
#pragma unroll
                    for (int cn = 0; cn < 4; ++cn) acc[r][cn] += a[r] * b[cn];
            }
            __syncthreads();
        }
    }
#pragma unroll
    for (int r = 0; r < 4; ++r)
#pragma unroll
        for (int cn = 0; cn < 4; ++cn)
            atomicAdd(&G[(size_t)(i0 + (ty << 2) + r) * Cc + j0 + (tx << 2) + cn],
                      acc[r][cn]);
}

__global__ __launch_bounds__(256) void sigman_full_kernel(const float* __restrict__ G,
                                                          const float* __restrict__ mean,
                                                          const float* __restrict__ scal,
                                                          float* __restrict__ S,
                                                          float* __restrict__ P) {
    const int e = blockIdx.x * 256 + threadIdx.x;
    const int i = e >> 9, j = e & 511;
    const float rtr = scal[0];
    float sig = G[e] * (1.0f / Mm) - mean[i] * mean[j];
    if (i == j) sig += EPSC;
    S[e] = sig * rtr;
    P[e] = (i == j) ? 1.f : 0.f;
}

__global__ __launch_bounds__(256) void mm512_kernel(const float* __restrict__ A,
                                                    const float* __restrict__ B,
                                                    float* __restrict__ C,
                                                    float alpha,
                                                    const float* __restrict__ D,
                                                    float beta) {
    const int ti = blockIdx.x >> 3, tj = blockIdx.x & 7;
    const int i0 = ti << 6, j0 = tj << 6;
    const int t  = threadIdx.x;
    const int tx = t & 15, ty = t >> 4;
    __shared__ float As[64][33];
    __shared__ float Bs[32][65];
    float acc[4][4] = {};
    const int lcA = t & 31, lrA = t >> 5;
    const int lcB = t & 63, lrB = t >> 6;
    for (int k0 = 0; k0 < 512; k0 += 32) {
#pragma unroll
        for (int r = 0; r < 8; ++r) {
            const int row = lrA + (r << 3);
            As[row][lcA] = A[(size_t)(i0 + row) * 512 + k0 + lcA];
        }
#pragma unroll
        for (int r = 0; r < 8; ++r) {
            const int row = lrB + (r << 2);
            Bs[row][lcB] = B[(size_t)(k0 + row) * 512 + j0 + lcB];
        }
        __syncthreads();
#pragma unroll
        for (int k = 0; k < 32; ++k) {
            float a[4], b[4];
#pragma unroll
            for (int r = 0; r < 4; ++r) a[r] = As[(ty << 2) + r][k];
#pragma unroll
            for (int cn = 0; cn < 4; ++cn) b[cn] = Bs[k][(tx << 2) + cn];
#pragma unroll
            for (int r = 0; r < 4; ++r)
#pragma unroll
                for (int cn = 0; cn < 4; ++cn) acc[r][cn] += a[r] * b[cn];
        }
        __syncthreads();
    }
#pragma unroll
    for (int r = 0; r < 4; ++r) {
        const size_t idx = (size_t)(i0 + (ty << 2) + r) * 512 + j0 + (tx << 2);
        float4 v;
        v.x = alpha * acc[r][0];
        v.y = alpha * acc[r][1];
        v.z = alpha * acc[r][2];
        v.w = alpha * acc[r][3];
        if (D) {
            const float4 d = *(const float4*)(D + idx);
            v.x += beta * d.x; v.y += beta * d.y; v.z += beta * d.z; v.w += beta * d.w;
        }
        *(float4*)(C + idx) = v;
    }
}

__global__ __launch_bounds__(128) void wmm_kernel(const float* __restrict__ P,
                                                  const float* __restrict__ mean,
                                                  const float* __restrict__ scal,
                                                  float* __restrict__ wmm) {
    const int c = blockIdx.x, t = threadIdx.x;
    float s = 0.f;
    for (int j = t; j < Cc; j += 128) s += P[(size_t)c * Cc + j] * mean[j];
    __shared__ float red[128];
    red[t] = s;
    __syncthreads();
    for (int o = 64; o > 0; o >>= 1) {
        if (t < o) red[t] += red[t + o];
        __syncthreads();
    }
    if (t == 0) wmm[c] = red[0] * scal[1];
}

__global__ __launch_bounds__(256) void whiten_kernel(const float* __restrict__ X,
                                                     const float* __restrict__ P,
                                                     const float* __restrict__ wmm,
                                                     const float* __restrict__ scal,
                                                     float* __restrict__ out) {
    const int c0 = blockIdx.x << 6;
    const int h0 = blockIdx.y << 6;
    const int n  = blockIdx.z;
    const int t  = threadIdx.x;
    const int tx = t & 15, ty = t >> 4;
    __shared__ float Ps[64][33];
    __shared__ float Xs[32][65];
    float acc[4][4] = {};
    const int lcA = t & 31, lrA = t >> 5;
    const int lcB = t & 63, lrB = t >> 6;
    const float* Xn = X + (size_t)n * CHW;
    for (int k0 = 0; k0 < 512; k0 += 32) {
#pragma unroll
        for (int r = 0; r < 8; ++r) {
            const int row = lrA + (r << 3);
            Ps[row][lcA] = P[(size_t)(c0 + row) * 512 + k0 + lcA];
        }
#pragma unroll
        for (int r = 0; r < 8; ++r) {
            const int row = lrB + (r << 2);
            Xs[row][lcB] = Xn[(size_t)(k0 + row) * HWs + h0 + lcB];
        }
        __syncthreads();
#pragma unroll
        for (int k = 0; k < 32; ++k) {
            float a[4], b[4];
#pragma unroll
            for (int r = 0; r < 4; ++r) a[r] = Ps[(ty << 2) + r][k];
#pragma unroll
            for (int cn = 0; cn < 4; ++cn) b[cn] = Xs[k][(tx << 2) + cn];
#pragma unroll
            for (int r = 0; r < 4; ++r)
#pragma unroll
                for (int cn = 0; cn < 4; ++cn) acc[r][cn] += a[r] * b[cn];
        }
        __syncthreads();
    }
    const float sr = scal[1];
#pragma unroll
    for (int r = 0; r < 4; ++r) {
        const int c = c0 + (ty << 2) + r;
        const float wv = wmm[c];
        float4 v;
        v.x = sr * acc[r][0] - wv;
        v.y = sr * acc[r][1] - wv;
        v.z = sr * acc[r][2] - wv;
        v.w = sr * acc[r][3] - wv;
        *(float4*)(out + (size_t)n * CHW + (size_t)c * HWs + h0 + (tx << 2)) = v;
    }
}

// ---------------------------------------------------------------------------
extern "C" void kernel_launch(void* const* d_in, const int* in_sizes, int n_in,
                              void* d_out, int out_size, void* d_ws, size_t ws_size,
                              hipStream_t stream) {
    const float* X = (const float*)d_in[0];
    float* out     = (float*)d_out;

    const size_t NU16 = 33554432;   // CHW*Nn
    const size_t NM   = 262144;     // 512*512
    const size_t NEED = NU16 * 2 * 2                              // Xbf + Xt
                      + NM * 10 * 2                               // 10 bf16 512x512 mats
                      + (NM + 8192 + 32 + 512 + 512 + 2 * NM) * 4;// G,meanP,scal+bar,mean,wmm,PfA/B

    if (ws_size >= NEED) {
        u16* Xbf = (u16*)d_ws;
        u16* Xt  = Xbf + NU16;
        u16* Sh  = Xt  + NU16;
        u16* Sl  = Sh + NM;
        u16* PhA = Sl + NM;
        u16* PlA = PhA + NM;
        u16* PhB = PlA + NM;
        u16* PlB = PhB + NM;
        u16* T2h = PlB + NM;
        u16* T2l = T2h + NM;
        u16* Wh  = T2l + NM;
        u16* Wl  = Wh + NM;
        float* G     = (float*)(Wl + NM);
        float* meanP = G + NM;               // 16*512 partials
        float* scal  = meanP + 8192;         // 16 floats
        int*   bar   = (int*)(scal + 16);    // 16 ints (grid barrier)
        float* mean  = (float*)(bar + 16);   // 512 (unused in fast path)
        float* wmm   = mean + 512;           // 512 (atomic-combined -> must be zeroed)
        float* PfA   = wmm + 512;            // 262144
        float* PfB   = PfA + NM;             // 262144

        // zero G + meanP + scal + bar + mean + wmm in one memset (contiguous)
        hipMemsetAsync(G, 0, (NM + 8192 + 32 + 1024) * sizeof(float), stream);
        convert_transpose<<<dim3(16, 8, 64), 256, 0, stream>>>(X, Xbf, Xt, meanP);
        gram_mfma<<<320, 256, 0, stream>>>(Xbf, G);
        ns_chain<<<NBC, 256, 0, stream>>>(G, meanP, scal, bar, wmm,
                                          Sh, Sl, PhA, PlA, PhB, PlB,
                                          T2h, T2l, Wh, Wl, PfA, PfB);
        whiten_mfma<<<1024, 256, 0, stream>>>(Xt, PhA, wmm, scal, out);
    } else {
        // fallback: fp32 path (~6.3 MB ws)
        float* ws   = (float*)d_ws;
        float* mean = ws;
        float* wmm  = ws + 512;
        float* scal = ws + 1024;
        float* G    = ws + 2048;
        float* S    = G + 262144;
        float* Pa   = S + 262144;
        float* Pb   = Pa + 262144;
        float* P2   = Pb + 262144;
        float* P3   = P2 + 262144;

        mean_kernel<<<512, 256, 0, stream>>>(X, mean);
        hipMemsetAsync(G, 0, sizeof(float) * 262144, stream);
        gram_kernel<<<dim3(64, 8), 256, 0, stream>>>(X, G);
        trace_fb<<<1, 256, 0, stream>>>(G, mean, scal);
        sigman_full_kernel<<<1024, 256, 0, stream>>>(G, mean, scal, S, Pa);

        float* P  = Pa;
        float* Pn = Pb;
        for (int it = 0; it < 5; ++it) {
            mm512_kernel<<<64, 256, 0, stream>>>(P, P, P2, 1.f, nullptr, 0.f);
            mm512_kernel<<<64, 256, 0, stream>>>(P2, P, P3, 1.f, nullptr, 0.f);
            mm512_kernel<<<64, 256, 0, stream>>>(P3, S, Pn, -0.5f, P, 1.5f);
            float* tmp = P; P = Pn; Pn = tmp;
        }

        wmm_kernel<<<512, 128, 0, stream>>>(P, mean, scal, wmm);
        whiten_kernel<<<dim3(8, 16, 64), 256, 0, stream>>>(X, P, wmm, scal, out);
    }
}